// Round 15
// baseline (1317.730 us; speedup 1.0000x reference)
//
#include <hip/hip_runtime.h>

// S4MaskNet: 2-layer S4, B=8, D=256, L=2048, N=32. Inputs f32, OUTPUT F32.
// r15: ROOT CAUSE FOUND — reference output dtype is float32 (JAX default);
// d_out is float*. All prior rounds wrote bf16 (= first half of the f32
// buffer); validator's f32 read saw untouched zeros at ref's argmax (second
// half) => error == max|ref| == 0.6328125 invariant. Harness was fine.
// Fix: final GEMMs store f32 to d_out. Intermediates remain bf16 in ws.

#define BSZ 8
#define DM 256
#define LSEQ 2048
#define NST 32
#define TOK (BSZ*LSEQ)
#define NL 2

__device__ __forceinline__ float b2f(unsigned short v) {
    unsigned int u = ((unsigned int)v) << 16;
    float f;
    __builtin_memcpy(&f, &u, 4);
    return f;
}
__device__ __forceinline__ unsigned short f2b(float f) {
    unsigned int u;
    __builtin_memcpy(&u, &f, 4);
    unsigned int r = (u + 0x7FFFu + ((u >> 16) & 1u)) >> 16;   // round-nearest-even
    return (unsigned short)r;
}
// erf via Abramowitz-Stegun 7.1.26 (max abs err 1.5e-7)
__device__ __forceinline__ float gelu_f(float z) {
    float x = z * 0.70710678118654752f;
    float ax = fabsf(x);
    float t = 1.0f / (1.0f + 0.3275911f * ax);
    float poly = t * (0.254829592f + t * (-0.284496736f + t * (1.421413741f +
                 t * (-1.453152027f + t * 1.061405429f))));
    float erfax = 1.0f - poly * expf(-ax * ax);
    float er = (x < 0.0f) ? -erfax : erfax;
    return 0.5f * z * (1.0f + er);
}

// ---- setup: dtA = dt*A, CB = C*B*(exp(dtA)-1)/A per (layer,h,n) ----
__global__ void k_setup_modes(const float* log_dt, const float* Alr, const float* Aim,
                              const float* Bre, const float* Bim,
                              const float* Cre, const float* Cim,
                              float* dtA_re, float* dtA_im, float* CB_re, float* CB_im) {
    int idx = blockIdx.x * blockDim.x + threadIdx.x;
    if (idx >= NL * DM * NST) return;
    int h = (idx >> 5) & (DM - 1);
    int i = idx >> 13;
    float dt  = expf(log_dt[i * DM + h]);
    float Are = -expf(Alr[idx]);
    float Ai  = Aim[idx];
    float dr = dt * Are, di = dt * Ai;
    float er = expf(dr);
    float lr = er * cosf(di), li = er * sinf(di);      // lambda = exp(dtA)
    float inv = 1.0f / (Are * Are + Ai * Ai);
    float e1r = lr - 1.0f, e1i = li;                   // lambda - 1
    float tr = (e1r * Are + e1i * Ai) * inv;           // (lambda-1)/A
    float ti = (e1i * Are - e1r * Ai) * inv;
    float br = Bre[idx], bi = Bim[idx];
    float dBr = br * tr - bi * ti, dBi = br * ti + bi * tr;
    float cr = Cre[idx], ci = Cim[idx];
    dtA_re[idx] = dr;
    dtA_im[idx] = di;
    CB_re[idx] = cr * dBr - ci * dBi;
    CB_im[idx] = cr * dBi + ci * dBr;
}

// ---- K[hg, l] = 2 Re sum_n CB*exp(dtA*l), hg in [0, NL*DM) ----
__global__ void k_Kfull(const float* dtA_re, const float* dtA_im,
                        const float* CB_re, const float* CB_im, float* Ktab) {
    int hg = blockIdx.x;
    int l = blockIdx.y * 256 + threadIdx.x;
    float fl = (float)l;
    float s = 0.0f;
    int base = hg * NST;
    for (int n = 0; n < NST; ++n) {
        float er = expf(dtA_re[base + n] * fl);
        float ph = dtA_im[base + n] * fl;
        float cs = cosf(ph), sn = sinf(ph);
        s += er * (CB_re[base + n] * cs - CB_im[base + n] * sn);
    }
    Ktab[(size_t)hg * LSEQ + l] = 2.0f * s;
}

// ---- x [B, D, L] f32 -> o [B, L, D] bf16 ----
__global__ void k_transpose_in(const float* x, unsigned short* o) {
    __shared__ float tile[32][33];
    int b = blockIdx.z;
    int l0 = blockIdx.x * 32, d0 = blockIdx.y * 32;
    int tx = threadIdx.x, ty = threadIdx.y;   // (32, 8)
    for (int k = 0; k < 4; ++k)
        tile[ty + 8 * k][tx] = x[((size_t)b * DM + d0 + ty + 8 * k) * LSEQ + l0 + tx];
    __syncthreads();
    for (int k = 0; k < 4; ++k)
        o[((size_t)b * LSEQ + l0 + ty + 8 * k) * DM + d0 + tx] = f2b(tile[tx][ty + 8 * k]);
}

// ---- layernorm over D (LDS tree reduction) ----
__global__ void k_layernorm(const unsigned short* src, unsigned short* dst,
                            const float* g, const float* bb) {
    __shared__ float r1[DM];
    __shared__ float r2[DM];
    int tok = blockIdx.x;
    int d = threadIdx.x;
    float v = b2f(src[(size_t)tok * DM + d]);
    r1[d] = v;
    r2[d] = v * v;
    __syncthreads();
    for (int s = DM / 2; s > 0; s >>= 1) {
        if (d < s) { r1[d] += r1[d + s]; r2[d] += r2[d + s]; }
        __syncthreads();
    }
    float m = r1[0] * (1.0f / DM);
    float var = r2[0] * (1.0f / DM) - m * m;
    float inv = rsqrtf(var + 1e-5f);
    dst[(size_t)tok * DM + d] = f2b((v - m) * inv * g[d] + bb[d]);
}

// ---- causal conv + D*u + gelu, IN-PLACE on u (full row staged in LDS) ----
__global__ void k_conv(int layer, unsigned short* u_io, const float* Ktab,
                       const float* Dp) {
    __shared__ float ub[LSEQ];    // 8 KB: whole row for this (b,h)
    __shared__ float Kw[512];     // sliding zero-padded K window
    int b = blockIdx.x, h = blockIdx.y;
    int tid = threadIdx.x;        // 256
    for (int i = tid; i < LSEQ; i += 256)
        ub[i] = b2f(u_io[((size_t)b * LSEQ + i) * DM + h]);
    __syncthreads();
    const float* Krow = Ktab + ((size_t)layer * DM + h) * LSEQ;
    float dp = Dp[layer * DM + h];
    for (int i = 0; i < LSEQ / 256; ++i) {        // output chunk
        float y = 0.0f;
        for (int j = 0; j <= i; ++j) {            // input chunk
            __syncthreads();
            int base = (i - j) * 256 - 255;       // Kw[w] = K[base+w], zero-padded
            int i0 = base + tid;
            Kw[tid] = (i0 >= 0 && i0 < LSEQ) ? Krow[i0] : 0.0f;
            int i1 = base + 256 + tid;
            Kw[256 + tid] = (i1 >= 0 && i1 < LSEQ) ? Krow[i1] : 0.0f;
            __syncthreads();
            int koff = tid + 255;
            int ubase = j * 256;
            for (int mm = 0; mm < 256; ++mm)
                y = fmaf(Kw[koff - mm], ub[ubase + mm], y);
        }
        int l = i * 256 + tid;
        float z = y + dp * ub[l];
        u_io[((size_t)b * LSEQ + l) * DM + h] = f2b(gelu_f(z));
    }
}

// ---- GEMM: [TOK,DM](bf16) @ [DM,N](f32) + bias, flagged epilogue ----
// flags: 1=gelu, 2=accumulate-read, 4=transposed-final-store(F32 to Cf), 8=relu
__global__ void k_gemm(const unsigned short* A, const float* W, const float* bias,
                       const unsigned short* res, unsigned short* C, float* Cf,
                       int N, int flags) {
    __shared__ float As[16][68];
    __shared__ float Bs[16][68];
    int m0 = blockIdx.x * 64, n0 = blockIdx.y * 64;
    int tid = threadIdx.x;
    int tx = tid & 15, ty = tid >> 4;
    float acc[4][4];
    for (int i = 0; i < 4; ++i)
        for (int j = 0; j < 4; ++j) acc[i][j] = 0.0f;
    for (int k0 = 0; k0 < DM; k0 += 16) {
        int row = tid >> 2, kq = (tid & 3) * 4;
        for (int q = 0; q < 4; ++q)
            As[kq + q][row] = b2f(A[(size_t)(m0 + row) * DM + k0 + kq + q]);
        int r = tid >> 4, cq = (tid & 15) * 4;
        for (int q = 0; q < 4; ++q)
            Bs[r][cq + q] = W[(size_t)(k0 + r) * N + n0 + cq + q];
        __syncthreads();
        for (int kk = 0; kk < 16; ++kk) {
            float av0 = As[kk][ty * 4 + 0], av1 = As[kk][ty * 4 + 1];
            float av2 = As[kk][ty * 4 + 2], av3 = As[kk][ty * 4 + 3];
            float bv0 = Bs[kk][tx * 4 + 0], bv1 = Bs[kk][tx * 4 + 1];
            float bv2 = Bs[kk][tx * 4 + 2], bv3 = Bs[kk][tx * 4 + 3];
            acc[0][0] = fmaf(av0, bv0, acc[0][0]); acc[0][1] = fmaf(av0, bv1, acc[0][1]);
            acc[0][2] = fmaf(av0, bv2, acc[0][2]); acc[0][3] = fmaf(av0, bv3, acc[0][3]);
            acc[1][0] = fmaf(av1, bv0, acc[1][0]); acc[1][1] = fmaf(av1, bv1, acc[1][1]);
            acc[1][2] = fmaf(av1, bv2, acc[1][2]); acc[1][3] = fmaf(av1, bv3, acc[1][3]);
            acc[2][0] = fmaf(av2, bv0, acc[2][0]); acc[2][1] = fmaf(av2, bv1, acc[2][1]);
            acc[2][2] = fmaf(av2, bv2, acc[2][2]); acc[2][3] = fmaf(av2, bv3, acc[2][3]);
            acc[3][0] = fmaf(av3, bv0, acc[3][0]); acc[3][1] = fmaf(av3, bv1, acc[3][1]);
            acc[3][2] = fmaf(av3, bv2, acc[3][2]); acc[3][3] = fmaf(av3, bv3, acc[3][3]);
        }
        __syncthreads();
    }
    for (int i = 0; i < 4; ++i) {
        int m = m0 + ty * 4 + i;
        int bb = m >> 11, l = m & 2047;   // token -> (batch, pos)
        for (int j = 0; j < 4; ++j) {
            int n = n0 + tx * 4 + j;
            float v = acc[i][j] + bias[n];
            if (res) v += b2f(res[(size_t)m * DM + n]);
            if (flags & 4) {
                // final store: F32, transposed to out[s][b][c][l]
                size_t idx = (((size_t)(n >> 8) * BSZ + bb) * DM + (n & 255)) * LSEQ + l;
                if (flags & 2) v += Cf[idx];
                if (flags & 8) v = fmaxf(v, 0.0f);
                Cf[idx] = v;
            } else {
                size_t idx = (size_t)m * N + n;
                if (flags & 2) v += b2f(C[idx]);
                if (flags & 1) v = gelu_f(v);
                C[idx] = f2b(v);
            }
        }
    }
}

// ---- launcher ----
extern "C" void kernel_launch(void* const* d_in, const int* in_sizes, int n_in,
                              void* d_out, int out_size, void* d_ws, size_t ws_size,
                              hipStream_t stream) {
    (void)in_sizes; (void)n_in; (void)out_size;
    float* out = (float*)d_out;   // F32 output (reference returns float32)

    const float* x      = (const float*)d_in[0];
    const float* ln_g   = (const float*)d_in[1];
    const float* ln_b   = (const float*)d_in[2];
    const float* log_dt = (const float*)d_in[3];
    const float* Alr    = (const float*)d_in[4];
    const float* Aim    = (const float*)d_in[5];
    const float* Bre    = (const float*)d_in[6];
    const float* Bim    = (const float*)d_in[7];
    const float* Cre    = (const float*)d_in[8];
    const float* Cim    = (const float*)d_in[9];
    const float* Dp     = (const float*)d_in[10];
    const float* s4oW   = (const float*)d_in[11];
    const float* s4ob   = (const float*)d_in[12];
    const float* lin1W  = (const float*)d_in[13];
    const float* lin1b  = (const float*)d_in[14];
    const float* lin2W  = (const float*)d_in[15];
    const float* lin2b  = (const float*)d_in[16];
    const float* headW0 = (const float*)d_in[17];
    const float* headb0 = (const float*)d_in[18];
    const float* projW0 = (const float*)d_in[19];
    const float* projb0 = (const float*)d_in[20];
    const float* headW1 = (const float*)d_in[21];
    const float* headb1 = (const float*)d_in[22];
    const float* projW1 = (const float*)d_in[23];
    const float* projb1 = (const float*)d_in[24];

    char* w = (char*)d_ws;
    unsigned short* A0 = (unsigned short*)w;  w += (size_t)TOK * DM * 2;   // 8 MiB
    unsigned short* A1 = (unsigned short*)w;  w += (size_t)TOK * DM * 2;
    unsigned short* A2 = (unsigned short*)w;  w += (size_t)TOK * DM * 2;
    float* Ktab   = (float*)w;                w += (size_t)NL * DM * LSEQ * 4;  // 4 MiB
    float* dtA_re = (float*)w;                w += (size_t)NL * DM * NST * 4;
    float* dtA_im = (float*)w;                w += (size_t)NL * DM * NST * 4;
    float* CB_re  = (float*)w;                w += (size_t)NL * DM * NST * 4;
    float* CB_im  = (float*)w;                w += (size_t)NL * DM * NST * 4;
    size_t used = (size_t)(w - (char*)d_ws);
    if (used > ws_size) return;   // verified fits (r11 watermark B)

    k_setup_modes<<<NL * DM * NST / 256, 256, 0, stream>>>(
        log_dt, Alr, Aim, Bre, Bim, Cre, Cim, dtA_re, dtA_im, CB_re, CB_im);
    {
        dim3 gk(NL * DM, LSEQ / 256);
        k_Kfull<<<gk, 256, 0, stream>>>(dtA_re, dtA_im, CB_re, CB_im, Ktab);
    }
    {
        dim3 gt(LSEQ / 32, DM / 32, BSZ);
        dim3 bt(32, 8);
        k_transpose_in<<<gt, bt, 0, stream>>>(x, A0);
    }

    dim3 gg(TOK / 64, DM / 64);
    dim3 gcv(BSZ, DM);
    // ---- layer 0 (u = A0) ----
    k_layernorm<<<TOK, DM, 0, stream>>>(A0, A1, ln_g + 0 * DM, ln_b + 0 * DM);
    k_conv<<<gcv, 256, 0, stream>>>(0, A1, Ktab, Dp);                           // A1 = gelu conv out
    k_gemm<<<gg, 256, 0, stream>>>(A1, s4oW, s4ob, 0, A2, 0, DM, 0);            // A2 = s4 out
    k_gemm<<<gg, 256, 0, stream>>>(A2, lin1W, lin1b, A0, A1, 0, DM, 0);         // A1 = o1 (+res u)
    k_layernorm<<<TOK, DM, 0, stream>>>(A1, A0, ln_g + 1 * DM, ln_b + 1 * DM);
    k_gemm<<<gg, 256, 0, stream>>>(A0, lin2W, lin2b, 0, A2, 0, DM, 1);          // A2 = gelu(o2 lin2)
    k_gemm<<<gg, 256, 0, stream>>>(A2, headW0, headb0, 0, A0, 0, DM, 0);        // A0 = head
    k_gemm<<<gg, 256, 0, stream>>>(A1, projW0, projb0, 0, A0, 0, DM, 2);        // A0 += proj
    // ---- layer 1 (u = A0) ----
    k_layernorm<<<TOK, DM, 0, stream>>>(A0, A1, ln_g + 2 * DM, ln_b + 2 * DM);
    k_conv<<<gcv, 256, 0, stream>>>(1, A1, Ktab, Dp);
    k_gemm<<<gg, 256, 0, stream>>>(A1, s4oW + (size_t)DM * DM, s4ob + DM, 0, A2, 0, DM, 0);
    k_gemm<<<gg, 256, 0, stream>>>(A2, lin1W + (size_t)DM * DM, lin1b + DM, A0, A1, 0, DM, 0);
    k_layernorm<<<TOK, DM, 0, stream>>>(A1, A0, ln_g + 3 * DM, ln_b + 3 * DM);
    k_gemm<<<gg, 256, 0, stream>>>(A0, lin2W + (size_t)DM * DM, lin2b + DM, 0, A2, 0, DM, 1);
    {
        dim3 gh(TOK / 64, 2 * DM / 64);
        // finals: F32 transposed stores into d_out
        k_gemm<<<gh, 256, 0, stream>>>(A2, headW1, headb1, 0, 0, out, 2 * DM, 4);
        k_gemm<<<gh, 256, 0, stream>>>(A1, projW1, projb1, 0, 0, out, 2 * DM, 4 | 2 | 8);
    }
}

// Round 17
// 708.514 us; speedup vs baseline: 1.8599x; 1.8599x over previous
//
#include <hip/hip_runtime.h>

// S4MaskNet: 2-layer S4, B=8, D=256, L=2048, N=32. Inputs f32, OUTPUT f32.
// r17: fixes r16's in-place head0 GEMM race (input==output==A2). Uniform
// buffer rotation: cur=A0 (layer in/out), A1=o1 stream, A2=scratch; all
// GEMMs have input != output. Chunked-scan conv (r16 math, verified).

#define BSZ 8
#define DM 256
#define LSEQ 2048
#define NST 32
#define TC 64
#define NCH 32           // LSEQ/TC
#define TOK (BSZ*LSEQ)
#define NL 2

__device__ __forceinline__ float b2f(unsigned short v) {
    unsigned int u = ((unsigned int)v) << 16;
    float f;
    __builtin_memcpy(&f, &u, 4);
    return f;
}
__device__ __forceinline__ unsigned short f2b(float f) {
    unsigned int u;
    __builtin_memcpy(&u, &f, 4);
    unsigned int r = (u + 0x7FFFu + ((u >> 16) & 1u)) >> 16;   // round-nearest-even
    return (unsigned short)r;
}
__device__ __forceinline__ float gelu_f(float z) {
    float x = z * 0.70710678118654752f;
    float ax = fabsf(x);
    float t = 1.0f / (1.0f + 0.3275911f * ax);
    float poly = t * (0.254829592f + t * (-0.284496736f + t * (1.421413741f +
                 t * (-1.453152027f + t * 1.061405429f))));
    float erfax = 1.0f - poly * expf(-ax * ax);
    float er = (x < 0.0f) ? -erfax : erfax;
    return 0.5f * z * (1.0f + er);
}

// ---- setup: dtA, lambda=exp(dtA), lambda^TC, CB = C*B*(lambda-1)/A ----
__global__ void k_setup_modes(const float* log_dt, const float* Alr, const float* Aim,
                              const float* Bre, const float* Bim,
                              const float* Cre, const float* Cim,
                              float2* dtA, float2* lam, float2* lamT, float2* CB) {
    int idx = blockIdx.x * blockDim.x + threadIdx.x;
    if (idx >= NL * DM * NST) return;
    int h = (idx >> 5) & (DM - 1);
    int i = idx >> 13;
    float dt  = expf(log_dt[i * DM + h]);
    float Are = -expf(Alr[idx]);
    float Ai  = Aim[idx];
    float dr = dt * Are, di = dt * Ai;
    float er = expf(dr);
    float lr = er * cosf(di), li = er * sinf(di);
    float inv = 1.0f / (Are * Are + Ai * Ai);
    float e1r = lr - 1.0f, e1i = li;
    float tr = (e1r * Are + e1i * Ai) * inv;
    float ti = (e1i * Are - e1r * Ai) * inv;
    float br = Bre[idx], bi = Bim[idx];
    float dBr = br * tr - bi * ti, dBi = br * ti + bi * tr;
    float cr = Cre[idx], ci = Cim[idx];
    dtA[idx] = make_float2(dr, di);
    lam[idx] = make_float2(lr, li);
    CB[idx]  = make_float2(cr * dBr - ci * dBi, cr * dBi + ci * dBr);
    float pr = lr, pi = li;                 // lambda^64 by 6 squarings
    for (int s = 0; s < 6; ++s) { float nr = pr * pr - pi * pi; pi = 2.f * pr * pi; pr = nr; }
    lamT[idx] = make_float2(pr, pi);
}

// ---- chunk tables (per layer): Ktab[h*TC+t]=2Re sum CB lam^t; Wtab=CB lam^(t+1) ----
__global__ void k_setup_wk(const float2* dtA_l, const float2* lam_l, const float2* CB_l,
                           float* Ktab, float2* Wtab) {
    int idx = blockIdx.x * blockDim.x + threadIdx.x;   // h*TC + t
    if (idx >= DM * TC) return;
    int t = idx & (TC - 1);
    int h = idx >> 6;
    int base = h * NST;
    float ft = (float)t;
    float Ks = 0.f;
    for (int n = 0; n < NST; ++n) {
        float2 d = dtA_l[base + n]; float2 l1 = lam_l[base + n]; float2 cb = CB_l[base + n];
        float er = expf(d.x * ft);
        float cs = cosf(d.y * ft), sn = sinf(d.y * ft);
        float ltr = er * cs, lti = er * sn;                         // lambda^t
        Ks += cb.x * ltr - cb.y * lti;
        float p1r = ltr * l1.x - lti * l1.y, p1i = ltr * l1.y + lti * l1.x;  // lambda^(t+1)
        Wtab[(h * NST + n) * TC + t] =
            make_float2(cb.x * p1r - cb.y * p1i, cb.x * p1i + cb.y * p1r);
    }
    Ktab[idx] = 2.f * Ks;
}

// ---- x [B, D, L] f32 -> o [B, L, D] bf16 ----
__global__ void k_transpose_in(const float* x, unsigned short* o) {
    __shared__ float tile[32][33];
    int b = blockIdx.z;
    int l0 = blockIdx.x * 32, d0 = blockIdx.y * 32;
    int tx = threadIdx.x, ty = threadIdx.y;
    for (int k = 0; k < 4; ++k)
        tile[ty + 8 * k][tx] = x[((size_t)b * DM + d0 + ty + 8 * k) * LSEQ + l0 + tx];
    __syncthreads();
    for (int k = 0; k < 4; ++k)
        o[((size_t)b * LSEQ + l0 + ty + 8 * k) * DM + d0 + tx] = f2b(tile[tx][ty + 8 * k]);
}

// ---- layernorm over D ----
__global__ void k_layernorm(const unsigned short* src, unsigned short* dst,
                            const float* g, const float* bb) {
    __shared__ float r1[DM];
    __shared__ float r2[DM];
    int tok = blockIdx.x;
    int d = threadIdx.x;
    float v = b2f(src[(size_t)tok * DM + d]);
    r1[d] = v;
    r2[d] = v * v;
    __syncthreads();
    for (int s = DM / 2; s > 0; s >>= 1) {
        if (d < s) { r1[d] += r1[d + s]; r2[d] += r2[d + s]; }
        __syncthreads();
    }
    float m = r1[0] * (1.0f / DM);
    float var = r2[0] * (1.0f / DM) - m * m;
    float inv = rsqrtf(var + 1e-5f);
    dst[(size_t)tok * DM + d] = f2b((v - m) * inv * g[d] + bb[d]);
}

// ---- chunk states: P[b,h,c,n] = sum_t lam^(TC-1-t) u[cT+t] ----
__global__ void k_chunk_states(const unsigned short* uln, const float2* lam_l,
                               float2* P) {
    int n = threadIdx.x & 31, hs = threadIdx.x >> 5;   // 256 thr: 32n x 8h
    int c = blockIdx.x, h = blockIdx.y * 8 + hs, b = blockIdx.z;
    float2 lm = lam_l[h * NST + n];
    float sr = 0.f, si = 0.f;
    const unsigned short* up = uln + ((size_t)(b * LSEQ + c * TC)) * DM + h;
#pragma unroll 4
    for (int t = 0; t < TC; ++t) {
        float u = b2f(up[(size_t)t * DM]);
        float nr = fmaf(lm.x, sr, fmaf(-lm.y, si, u));
        float ni = fmaf(lm.x, si, lm.y * sr);
        sr = nr; si = ni;
    }
    P[(((size_t)b * DM + h) * NCH + c) * NST + n] = make_float2(sr, si);
}

// ---- scan: in-place, P[c] becomes S(c) = state at end of chunk c-1 ----
__global__ void k_chunk_scan(const float2* lamT_l, float2* P) {
    int idx = blockIdx.x * blockDim.x + threadIdx.x;
    if (idx >= BSZ * DM * NST) return;
    int n = idx & 31, h = (idx >> 5) & 255, b = idx >> 13;
    float2 lT = lamT_l[h * NST + n];
    float hr = 0.f, hi = 0.f;
    float2* base = P + (((size_t)b * DM + h) * NCH) * NST + n;
    for (int c = 0; c < NCH; ++c) {
        float2 p = base[(size_t)c * NST];
        base[(size_t)c * NST] = make_float2(hr, hi);
        float nr = fmaf(lT.x, hr, fmaf(-lT.y, hi, p.x));
        float ni = fmaf(lT.x, hi, fmaf(lT.y, hr, p.y));
        hr = nr; hi = ni;
    }
}

// ---- conv out (chunk): y = intra-Toeplitz + 2Re sum_n W[n][t] S_n + Dp*u; gelu ----
__global__ void k_conv_out(unsigned short* u_io, const float* Ktab,
                           const float2* Wtab, const float2* S,
                           const float* Dp_l) {
    int c = blockIdx.x, h = blockIdx.y;
    int tid = threadIdx.x;                      // 128 = 8b x 16q
    __shared__ float  Kch[TC];
    __shared__ float2 Wt[NST][TC];
    __shared__ float  uch[BSZ][TC];
    __shared__ float2 hst[BSZ][NST];
    if (tid < TC) Kch[tid] = Ktab[h * TC + tid];
    for (int idx = tid; idx < NST * TC; idx += 128)
        Wt[idx >> 6][idx & 63] = Wtab[(size_t)h * NST * TC + idx];
    for (int idx = tid; idx < BSZ * TC; idx += 128) {
        int b = idx >> 6, t = idx & 63;
        uch[b][t] = b2f(u_io[((size_t)(b * LSEQ + c * TC + t)) * DM + h]);
    }
    for (int idx = tid; idx < BSZ * NST; idx += 128) {
        int b = idx >> 5, n = idx & 31;
        hst[b][n] = S[(((size_t)b * DM + h) * NCH + c) * NST + n];
    }
    __syncthreads();
    int b = tid >> 4, q = tid & 15, t0 = q * 4;
    float s0 = 0, s1 = 0, s2 = 0, s3 = 0;
    float u0 = uch[b][t0], u1 = uch[b][t0 + 1], u2 = uch[b][t0 + 2], u3 = uch[b][t0 + 3];
    for (int d = 0; d <= t0; ++d) {
        float kk = Kch[d];
        s0 = fmaf(kk, u0, s0); s1 = fmaf(kk, u1, s1);
        s2 = fmaf(kk, u2, s2); s3 = fmaf(kk, u3, s3);
        u3 = u2; u2 = u1; u1 = u0;
        u0 = (d < t0) ? uch[b][t0 - d - 1] : 0.f;
    }
    {   // tail d = t0+1..t0+3; here u1=uch[0], u2=uch[1], u3=uch[2]
        float k1 = Kch[t0 + 1], k2 = Kch[t0 + 2], k3 = Kch[t0 + 3];
        s1 = fmaf(k1, u1, s1); s2 = fmaf(k1, u2, s2); s3 = fmaf(k1, u3, s3);
        s2 = fmaf(k2, u1, s2); s3 = fmaf(k2, u2, s3);
        s3 = fmaf(k3, u1, s3);
    }
    float y0 = 0, y1 = 0, y2 = 0, y3 = 0;
#pragma unroll
    for (int n = 0; n < NST; ++n) {
        float2 hh = hst[b][n];
        float2 w0 = Wt[n][t0], w1 = Wt[n][t0 + 1], w2 = Wt[n][t0 + 2], w3 = Wt[n][t0 + 3];
        y0 += w0.x * hh.x - w0.y * hh.y;
        y1 += w1.x * hh.x - w1.y * hh.y;
        y2 += w2.x * hh.x - w2.y * hh.y;
        y3 += w3.x * hh.x - w3.y * hh.y;
    }
    float dp = Dp_l[h];
    size_t obase = ((size_t)(b * LSEQ + c * TC + t0)) * DM + h;
    float z;
    z = s0 + 2.f * y0 + dp * uch[b][t0];     u_io[obase]          = f2b(gelu_f(z));
    z = s1 + 2.f * y1 + dp * uch[b][t0 + 1]; u_io[obase + DM]     = f2b(gelu_f(z));
    z = s2 + 2.f * y2 + dp * uch[b][t0 + 2]; u_io[obase + 2 * DM] = f2b(gelu_f(z));
    z = s3 + 2.f * y3 + dp * uch[b][t0 + 3]; u_io[obase + 3 * DM] = f2b(gelu_f(z));
}

// ---- GEMM: [TOK,DM](bf16) @ [DM,N](f32) + bias, flagged epilogue ----
// flags: 1=gelu, 2=accumulate-read, 4=transposed-final-store(F32->Cf), 8=relu
__global__ void k_gemm(const unsigned short* A, const float* W, const float* bias,
                       const unsigned short* res, unsigned short* C, float* Cf,
                       int N, int flags) {
    __shared__ float As[16][68];
    __shared__ float Bs[16][68];
    int m0 = blockIdx.x * 64, n0 = blockIdx.y * 64;
    int tid = threadIdx.x;
    int tx = tid & 15, ty = tid >> 4;
    float acc[4][4];
    for (int i = 0; i < 4; ++i)
        for (int j = 0; j < 4; ++j) acc[i][j] = 0.0f;
    for (int k0 = 0; k0 < DM; k0 += 16) {
        int row = tid >> 2, kq = (tid & 3) * 4;
        for (int q = 0; q < 4; ++q)
            As[kq + q][row] = b2f(A[(size_t)(m0 + row) * DM + k0 + kq + q]);
        int r = tid >> 4, cq = (tid & 15) * 4;
        for (int q = 0; q < 4; ++q)
            Bs[r][cq + q] = W[(size_t)(k0 + r) * N + n0 + cq + q];
        __syncthreads();
        for (int kk = 0; kk < 16; ++kk) {
            float av0 = As[kk][ty * 4 + 0], av1 = As[kk][ty * 4 + 1];
            float av2 = As[kk][ty * 4 + 2], av3 = As[kk][ty * 4 + 3];
            float bv0 = Bs[kk][tx * 4 + 0], bv1 = Bs[kk][tx * 4 + 1];
            float bv2 = Bs[kk][tx * 4 + 2], bv3 = Bs[kk][tx * 4 + 3];
            acc[0][0] = fmaf(av0, bv0, acc[0][0]); acc[0][1] = fmaf(av0, bv1, acc[0][1]);
            acc[0][2] = fmaf(av0, bv2, acc[0][2]); acc[0][3] = fmaf(av0, bv3, acc[0][3]);
            acc[1][0] = fmaf(av1, bv0, acc[1][0]); acc[1][1] = fmaf(av1, bv1, acc[1][1]);
            acc[1][2] = fmaf(av1, bv2, acc[1][2]); acc[1][3] = fmaf(av1, bv3, acc[1][3]);
            acc[2][0] = fmaf(av2, bv0, acc[2][0]); acc[2][1] = fmaf(av2, bv1, acc[2][1]);
            acc[2][2] = fmaf(av2, bv2, acc[2][2]); acc[2][3] = fmaf(av2, bv3, acc[2][3]);
            acc[3][0] = fmaf(av3, bv0, acc[3][0]); acc[3][1] = fmaf(av3, bv1, acc[3][1]);
            acc[3][2] = fmaf(av3, bv2, acc[3][2]); acc[3][3] = fmaf(av3, bv3, acc[3][3]);
        }
        __syncthreads();
    }
    for (int i = 0; i < 4; ++i) {
        int m = m0 + ty * 4 + i;
        int bb = m >> 11, l = m & 2047;
        for (int j = 0; j < 4; ++j) {
            int n = n0 + tx * 4 + j;
            float v = acc[i][j] + bias[n];
            if (res) v += b2f(res[(size_t)m * DM + n]);
            if (flags & 4) {
                size_t idx = (((size_t)(n >> 8) * BSZ + bb) * DM + (n & 255)) * LSEQ + l;
                if (flags & 2) v += Cf[idx];
                if (flags & 8) v = fmaxf(v, 0.0f);
                Cf[idx] = v;
            } else {
                size_t idx = (size_t)m * N + n;
                if (flags & 2) v += b2f(C[idx]);
                if (flags & 1) v = gelu_f(v);
                C[idx] = f2b(v);
            }
        }
    }
}

// ---- launcher ----
extern "C" void kernel_launch(void* const* d_in, const int* in_sizes, int n_in,
                              void* d_out, int out_size, void* d_ws, size_t ws_size,
                              hipStream_t stream) {
    (void)in_sizes; (void)n_in; (void)out_size;
    float* out = (float*)d_out;

    const float* x      = (const float*)d_in[0];
    const float* ln_g   = (const float*)d_in[1];
    const float* ln_b   = (const float*)d_in[2];
    const float* log_dt = (const float*)d_in[3];
    const float* Alr    = (const float*)d_in[4];
    const float* Aim    = (const float*)d_in[5];
    const float* Bre    = (const float*)d_in[6];
    const float* Bim    = (const float*)d_in[7];
    const float* Cre    = (const float*)d_in[8];
    const float* Cim    = (const float*)d_in[9];
    const float* Dp     = (const float*)d_in[10];
    const float* s4oW   = (const float*)d_in[11];
    const float* s4ob   = (const float*)d_in[12];
    const float* lin1W  = (const float*)d_in[13];
    const float* lin1b  = (const float*)d_in[14];
    const float* lin2W  = (const float*)d_in[15];
    const float* lin2b  = (const float*)d_in[16];
    const float* headW[2] = {(const float*)d_in[17], (const float*)d_in[21]};
    const float* headb[2] = {(const float*)d_in[18], (const float*)d_in[22]};
    const float* projW[2] = {(const float*)d_in[19], (const float*)d_in[23]};
    const float* projb[2] = {(const float*)d_in[20], (const float*)d_in[24]};

    char* w = (char*)d_ws;
    unsigned short* A0 = (unsigned short*)w;  w += (size_t)TOK * DM * 2;
    unsigned short* A1 = (unsigned short*)w;  w += (size_t)TOK * DM * 2;
    unsigned short* A2 = (unsigned short*)w;  w += (size_t)TOK * DM * 2;
    float2* dtA  = (float2*)w;                w += (size_t)NL * DM * NST * 8;
    float2* lam  = (float2*)w;                w += (size_t)NL * DM * NST * 8;
    float2* lamT = (float2*)w;                w += (size_t)NL * DM * NST * 8;
    float2* CB   = (float2*)w;                w += (size_t)NL * DM * NST * 8;
    float2* P    = (float2*)w;                w += (size_t)BSZ * DM * NCH * NST * 8;
    float2* Wtab = (float2*)w;                w += (size_t)DM * NST * TC * 8;
    float*  KtabC = (float*)w;                w += (size_t)DM * TC * 4;
    if ((size_t)(w - (char*)d_ws) > ws_size) return;  // 44.6 MiB; fits (r11-verified >=28.3, r16 ran chunk path)

    k_setup_modes<<<NL * DM * NST / 256, 256, 0, stream>>>(
        log_dt, Alr, Aim, Bre, Bim, Cre, Cim, dtA, lam, lamT, CB);
    {
        dim3 gt(LSEQ / 32, DM / 32, BSZ);
        dim3 bt(32, 8);
        k_transpose_in<<<gt, bt, 0, stream>>>(x, A0);
    }

    dim3 gg(TOK / 64, DM / 64);
    for (int i = 0; i < NL; ++i) {
        // cur=A0 (layer in/out), A1 = LN/conv/o1 stream, A2 = scratch.
        size_t off = (size_t)i * DM * NST;
        size_t wf  = (size_t)i * DM * DM;

        k_layernorm<<<TOK, DM, 0, stream>>>(A0, A1, ln_g + (2 * i) * DM,
                                            ln_b + (2 * i) * DM);
        k_setup_wk<<<DM * TC / 128, 128, 0, stream>>>(dtA + off, lam + off,
                                                      CB + off, KtabC, Wtab);
        {
            dim3 gs(NCH, DM / 8, BSZ);
            k_chunk_states<<<gs, 256, 0, stream>>>(A1, lam + off, P);
        }
        k_chunk_scan<<<BSZ * DM * NST / 256, 256, 0, stream>>>(lamT + off, P);
        {
            dim3 gc(NCH, DM);
            k_conv_out<<<gc, 128, 0, stream>>>(A1, KtabC, Wtab, P, Dp + i * DM);
        }
        // A1 (conv/gelu) @ s4oW -> A2 ; A2 @ lin1W + res(A0) -> A1 (= o1)
        k_gemm<<<gg, 256, 0, stream>>>(A1, s4oW + wf, s4ob + i * DM, 0, A2, 0, DM, 0);
        k_gemm<<<gg, 256, 0, stream>>>(A2, lin1W + wf, lin1b + i * DM, A0, A1, 0, DM, 0);
        // LN2(A1) -> A0 (u dead) ; gelu(A0 @ lin2W) -> A2
        k_layernorm<<<TOK, DM, 0, stream>>>(A1, A0, ln_g + (2 * i + 1) * DM,
                                            ln_b + (2 * i + 1) * DM);
        k_gemm<<<gg, 256, 0, stream>>>(A0, lin2W + wf, lin2b + i * DM, 0, A2, 0, DM, 1);
        if (i == 0) {
            // head0: A2 -> A0 (distinct); proj0: A1 accumulates -> A0. Layer out = A0.
            k_gemm<<<gg, 256, 0, stream>>>(A2, headW[0], headb[0], 0, A0, 0, DM, 0);
            k_gemm<<<gg, 256, 0, stream>>>(A1, projW[0], projb[0], 0, A0, 0, DM, 2);
        } else {
            dim3 gh(TOK / 64, 2 * DM / 64);
            k_gemm<<<gh, 256, 0, stream>>>(A2, headW[1], headb[1], 0, 0, out, 2 * DM, 4);
            k_gemm<<<gh, 256, 0, stream>>>(A1, projW[1], projb[1], 0, 0, out, 2 * DM, 4 | 2 | 8);
        }
    }
}

// Round 18
// 574.977 us; speedup vs baseline: 2.2918x; 1.2322x over previous
//
#include <hip/hip_runtime.h>

// S4MaskNet: 2-layer S4, B=8, D=256, L=2048, N=32. Inputs f32, OUTPUT f32.
// r18: (1) all GEMMs -> MFMA bf16 (pre-transposed bf16 weights WBt[n][k]);
// (2) final head/proj write row-major bf16 F (aliases P) + coalesced
// transpose kernel -> f32 out (kills 81MB f32 scatter);
// (3) conv_out LDS bank fixes (split Wre/Wim, pad uch/hst).

#define BSZ 8
#define DM 256
#define LSEQ 2048
#define NST 32
#define TC 64
#define NCH 32
#define TOK (BSZ*LSEQ)
#define NL 2

typedef __attribute__((ext_vector_type(8))) short bf16x8;
typedef __attribute__((ext_vector_type(4))) float f32x4;

__device__ __forceinline__ float b2f(unsigned short v) {
    unsigned int u = ((unsigned int)v) << 16;
    float f;
    __builtin_memcpy(&f, &u, 4);
    return f;
}
__device__ __forceinline__ unsigned short f2b(float f) {
    unsigned int u;
    __builtin_memcpy(&u, &f, 4);
    unsigned int r = (u + 0x7FFFu + ((u >> 16) & 1u)) >> 16;   // RNE
    return (unsigned short)r;
}
__device__ __forceinline__ float gelu_f(float z) {
    float x = z * 0.70710678118654752f;
    float ax = fabsf(x);
    float t = 1.0f / (1.0f + 0.3275911f * ax);
    float poly = t * (0.254829592f + t * (-0.284496736f + t * (1.421413741f +
                 t * (-1.453152027f + t * 1.061405429f))));
    float erfax = 1.0f - poly * expf(-ax * ax);
    float er = (x < 0.0f) ? -erfax : erfax;
    return 0.5f * z * (1.0f + er);
}

// ---- setup: dtA, lambda, lambda^TC, CB ----
__global__ void k_setup_modes(const float* log_dt, const float* Alr, const float* Aim,
                              const float* Bre, const float* Bim,
                              const float* Cre, const float* Cim,
                              float2* dtA, float2* lam, float2* lamT, float2* CB) {
    int idx = blockIdx.x * blockDim.x + threadIdx.x;
    if (idx >= NL * DM * NST) return;
    int h = (idx >> 5) & (DM - 1);
    int i = idx >> 13;
    float dt  = expf(log_dt[i * DM + h]);
    float Are = -expf(Alr[idx]);
    float Ai  = Aim[idx];
    float dr = dt * Are, di = dt * Ai;
    float er = expf(dr);
    float lr = er * cosf(di), li = er * sinf(di);
    float inv = 1.0f / (Are * Are + Ai * Ai);
    float e1r = lr - 1.0f, e1i = li;
    float tr = (e1r * Are + e1i * Ai) * inv;
    float ti = (e1i * Are - e1r * Ai) * inv;
    float br = Bre[idx], bi = Bim[idx];
    float dBr = br * tr - bi * ti, dBi = br * ti + bi * tr;
    float cr = Cre[idx], ci = Cim[idx];
    dtA[idx] = make_float2(dr, di);
    lam[idx] = make_float2(lr, li);
    CB[idx]  = make_float2(cr * dBr - ci * dBi, cr * dBi + ci * dBr);
    float pr = lr, pi = li;
    for (int s = 0; s < 6; ++s) { float nr = pr * pr - pi * pi; pi = 2.f * pr * pi; pr = nr; }
    lamT[idx] = make_float2(pr, pi);
}

// ---- weight convert+transpose: W[k][N] f32 -> WBt[n][256] bf16 ----
__global__ void k_wcvt(const float* src, unsigned short* dst, int N) {
    int idx = blockIdx.x * 256 + threadIdx.x;   // n*256 + k
    if (idx >= N * 256) return;
    int n = idx >> 8, k = idx & 255;
    dst[idx] = f2b(src[(size_t)k * N + n]);
}

// ---- chunk tables ----
__global__ void k_setup_wk(const float2* dtA_l, const float2* lam_l, const float2* CB_l,
                           float* Ktab, float2* Wtab) {
    int idx = blockIdx.x * blockDim.x + threadIdx.x;
    if (idx >= DM * TC) return;
    int t = idx & (TC - 1);
    int h = idx >> 6;
    int base = h * NST;
    float ft = (float)t;
    float Ks = 0.f;
    for (int n = 0; n < NST; ++n) {
        float2 d = dtA_l[base + n]; float2 l1 = lam_l[base + n]; float2 cb = CB_l[base + n];
        float er = expf(d.x * ft);
        float cs = cosf(d.y * ft), sn = sinf(d.y * ft);
        float ltr = er * cs, lti = er * sn;
        Ks += cb.x * ltr - cb.y * lti;
        float p1r = ltr * l1.x - lti * l1.y, p1i = ltr * l1.y + lti * l1.x;
        Wtab[(h * NST + n) * TC + t] =
            make_float2(cb.x * p1r - cb.y * p1i, cb.x * p1i + cb.y * p1r);
    }
    Ktab[idx] = 2.f * Ks;
}

// ---- x [B, D, L] f32 -> o [B, L, D] bf16 ----
__global__ void k_transpose_in(const float* x, unsigned short* o) {
    __shared__ float tile[32][33];
    int b = blockIdx.z;
    int l0 = blockIdx.x * 32, d0 = blockIdx.y * 32;
    int tx = threadIdx.x, ty = threadIdx.y;
    for (int k = 0; k < 4; ++k)
        tile[ty + 8 * k][tx] = x[((size_t)b * DM + d0 + ty + 8 * k) * LSEQ + l0 + tx];
    __syncthreads();
    for (int k = 0; k < 4; ++k)
        o[((size_t)b * LSEQ + l0 + ty + 8 * k) * DM + d0 + tx] = f2b(tile[tx][ty + 8 * k]);
}

// ---- layernorm ----
__global__ void k_layernorm(const unsigned short* src, unsigned short* dst,
                            const float* g, const float* bb) {
    __shared__ float r1[DM];
    __shared__ float r2[DM];
    int tok = blockIdx.x;
    int d = threadIdx.x;
    float v = b2f(src[(size_t)tok * DM + d]);
    r1[d] = v;
    r2[d] = v * v;
    __syncthreads();
    for (int s = DM / 2; s > 0; s >>= 1) {
        if (d < s) { r1[d] += r1[d + s]; r2[d] += r2[d + s]; }
        __syncthreads();
    }
    float m = r1[0] * (1.0f / DM);
    float var = r2[0] * (1.0f / DM) - m * m;
    float inv = rsqrtf(var + 1e-5f);
    dst[(size_t)tok * DM + d] = f2b((v - m) * inv * g[d] + bb[d]);
}

// ---- chunk states ----
__global__ void k_chunk_states(const unsigned short* uln, const float2* lam_l,
                               float2* P) {
    int n = threadIdx.x & 31, hs = threadIdx.x >> 5;
    int c = blockIdx.x, h = blockIdx.y * 8 + hs, b = blockIdx.z;
    float2 lm = lam_l[h * NST + n];
    float sr = 0.f, si = 0.f;
    const unsigned short* up = uln + ((size_t)(b * LSEQ + c * TC)) * DM + h;
#pragma unroll 4
    for (int t = 0; t < TC; ++t) {
        float u = b2f(up[(size_t)t * DM]);
        float nr = fmaf(lm.x, sr, fmaf(-lm.y, si, u));
        float ni = fmaf(lm.x, si, lm.y * sr);
        sr = nr; si = ni;
    }
    P[(((size_t)b * DM + h) * NCH + c) * NST + n] = make_float2(sr, si);
}

// ---- scan ----
__global__ void k_chunk_scan(const float2* lamT_l, float2* P) {
    int idx = blockIdx.x * blockDim.x + threadIdx.x;
    if (idx >= BSZ * DM * NST) return;
    int n = idx & 31, h = (idx >> 5) & 255, b = idx >> 13;
    float2 lT = lamT_l[h * NST + n];
    float hr = 0.f, hi = 0.f;
    float2* base = P + (((size_t)b * DM + h) * NCH) * NST + n;
    for (int c = 0; c < NCH; ++c) {
        float2 p = base[(size_t)c * NST];
        base[(size_t)c * NST] = make_float2(hr, hi);
        float nr = fmaf(lT.x, hr, fmaf(-lT.y, hi, p.x));
        float ni = fmaf(lT.x, hi, fmaf(lT.y, hr, p.y));
        hr = nr; hi = ni;
    }
}

// ---- conv out: split-array LDS (bank-conflict fixed) ----
__global__ void k_conv_out(unsigned short* u_io, const float* Ktab,
                           const float2* Wtab, const float2* S,
                           const float* Dp_l) {
    int c = blockIdx.x, h = blockIdx.y;
    int tid = threadIdx.x;                      // 128 = 8b x 16q
    __shared__ float Kch[TC];
    __shared__ float Wre[NST][TC];
    __shared__ float Wim[NST][TC];
    __shared__ float uch[BSZ][TC + 1];
    __shared__ float hre[BSZ][NST + 1];
    __shared__ float him[BSZ][NST + 1];
    if (tid < TC) Kch[tid] = Ktab[h * TC + tid];
    for (int idx = tid; idx < NST * TC; idx += 128) {
        float2 wv = Wtab[(size_t)h * NST * TC + idx];
        Wre[idx >> 6][idx & 63] = wv.x;
        Wim[idx >> 6][idx & 63] = wv.y;
    }
    for (int idx = tid; idx < BSZ * TC; idx += 128) {
        int b = idx >> 6, t = idx & 63;
        uch[b][t] = b2f(u_io[((size_t)(b * LSEQ + c * TC + t)) * DM + h]);
    }
    for (int idx = tid; idx < BSZ * NST; idx += 128) {
        int b = idx >> 5, n = idx & 31;
        float2 hv = S[(((size_t)b * DM + h) * NCH + c) * NST + n];
        hre[b][n] = hv.x;
        him[b][n] = hv.y;
    }
    __syncthreads();
    int b = tid >> 4, q = tid & 15, t0 = q * 4;
    float s0 = 0, s1 = 0, s2 = 0, s3 = 0;
    float u0 = uch[b][t0], u1 = uch[b][t0 + 1], u2 = uch[b][t0 + 2], u3 = uch[b][t0 + 3];
    for (int d = 0; d <= t0; ++d) {
        float kk = Kch[d];
        s0 = fmaf(kk, u0, s0); s1 = fmaf(kk, u1, s1);
        s2 = fmaf(kk, u2, s2); s3 = fmaf(kk, u3, s3);
        u3 = u2; u2 = u1; u1 = u0;
        u0 = (d < t0) ? uch[b][t0 - d - 1] : 0.f;
    }
    {
        float k1 = Kch[t0 + 1], k2 = Kch[t0 + 2], k3 = Kch[t0 + 3];
        s1 = fmaf(k1, u1, s1); s2 = fmaf(k1, u2, s2); s3 = fmaf(k1, u3, s3);
        s2 = fmaf(k2, u1, s2); s3 = fmaf(k2, u2, s3);
        s3 = fmaf(k3, u1, s3);
    }
    float y0 = 0, y1 = 0, y2 = 0, y3 = 0;
#pragma unroll
    for (int n = 0; n < NST; ++n) {
        float hr = hre[b][n], hi = him[b][n];
        y0 += Wre[n][t0] * hr - Wim[n][t0] * hi;
        y1 += Wre[n][t0 + 1] * hr - Wim[n][t0 + 1] * hi;
        y2 += Wre[n][t0 + 2] * hr - Wim[n][t0 + 2] * hi;
        y3 += Wre[n][t0 + 3] * hr - Wim[n][t0 + 3] * hi;
    }
    float dp = Dp_l[h];
    size_t obase = ((size_t)(b * LSEQ + c * TC + t0)) * DM + h;
    float z;
    z = s0 + 2.f * y0 + dp * uch[b][t0];     u_io[obase]          = f2b(gelu_f(z));
    z = s1 + 2.f * y1 + dp * uch[b][t0 + 1]; u_io[obase + DM]     = f2b(gelu_f(z));
    z = s2 + 2.f * y2 + dp * uch[b][t0 + 2]; u_io[obase + 2 * DM] = f2b(gelu_f(z));
    z = s3 + 2.f * y3 + dp * uch[b][t0 + 3]; u_io[obase + 3 * DM] = f2b(gelu_f(z));
}

// ---- MFMA GEMM: C[M,N](bf16) = A[TOK,256](bf16) @ WBt^T + bias ----
// WBt is [N][256] bf16 (pre-transposed). flags: 1=gelu, 2=accum, 8=relu.
// 64x64 tile, 4 waves; wave w owns rows [w*16, w*16+16).
__global__ void k_gemm_mfma(const unsigned short* A, const unsigned short* WBt,
                            const float* bias, const unsigned short* res,
                            unsigned short* C, int N, int flags) {
    int m0 = blockIdx.x * 64, n0 = blockIdx.y * 64;
    int tid = threadIdx.x;
    int wv = tid >> 6, l = tid & 63;
    int lr = l & 15, lk = (l >> 4) * 8;
    f32x4 acc0 = {0.f, 0.f, 0.f, 0.f};
    f32x4 acc1 = acc0, acc2 = acc0, acc3 = acc0;
    const unsigned short* arow = A + (size_t)(m0 + wv * 16 + lr) * 256 + lk;
    const unsigned short* bcol = WBt + (size_t)(n0 + lr) * 256 + lk;
#pragma unroll
    for (int k0 = 0; k0 < 256; k0 += 32) {
        bf16x8 a  = *(const bf16x8*)(arow + k0);
        bf16x8 b0 = *(const bf16x8*)(bcol + k0);
        bf16x8 b1 = *(const bf16x8*)(bcol + 16 * 256 + k0);
        bf16x8 b2 = *(const bf16x8*)(bcol + 32 * 256 + k0);
        bf16x8 b3 = *(const bf16x8*)(bcol + 48 * 256 + k0);
        acc0 = __builtin_amdgcn_mfma_f32_16x16x32_bf16(a, b0, acc0, 0, 0, 0);
        acc1 = __builtin_amdgcn_mfma_f32_16x16x32_bf16(a, b1, acc1, 0, 0, 0);
        acc2 = __builtin_amdgcn_mfma_f32_16x16x32_bf16(a, b2, acc2, 0, 0, 0);
        acc3 = __builtin_amdgcn_mfma_f32_16x16x32_bf16(a, b3, acc3, 0, 0, 0);
    }
    int em = m0 + wv * 16 + (l >> 4) * 4;   // C/D: row=(l>>4)*4+r, col=l&15
    int en = n0 + (l & 15);
    f32x4 accs[4] = {acc0, acc1, acc2, acc3};
#pragma unroll
    for (int nt = 0; nt < 4; ++nt) {
        int n = en + nt * 16;
        float bsv = bias[n];
#pragma unroll
        for (int r = 0; r < 4; ++r) {
            int m = em + r;
            float v = accs[nt][r] + bsv;
            if (res) v += b2f(res[(size_t)m * DM + n]);
            size_t idx = (size_t)m * N + n;
            if (flags & 2) v += b2f(C[idx]);
            if (flags & 1) v = gelu_f(v);
            if (flags & 8) v = fmaxf(v, 0.0f);
            C[idx] = f2b(v);
        }
    }
}

// ---- final: F [B,L,512] bf16 -> out [2,B,256,L] f32 (relu already applied) ----
__global__ void k_final_out(const unsigned short* F, float* out) {
    __shared__ float tile[32][33];
    int b = blockIdx.z;
    int l0 = blockIdx.x * 32, c0 = blockIdx.y * 32;
    int tx = threadIdx.x, ty = threadIdx.y;   // (32,8)
    for (int k = 0; k < 4; ++k)
        tile[ty + 8 * k][tx] = b2f(F[((size_t)(b * LSEQ + l0 + ty + 8 * k)) * 512 + c0 + tx]);
    __syncthreads();
    for (int k = 0; k < 4; ++k) {
        int cg = c0 + ty + 8 * k;
        int s = cg >> 8, cc = cg & 255;
        out[(((size_t)s * BSZ + b) * DM + cc) * LSEQ + l0 + tx] = tile[tx][ty + 8 * k];
    }
}

// ---- launcher ----
extern "C" void kernel_launch(void* const* d_in, const int* in_sizes, int n_in,
                              void* d_out, int out_size, void* d_ws, size_t ws_size,
                              hipStream_t stream) {
    (void)in_sizes; (void)n_in; (void)out_size;
    float* out = (float*)d_out;

    const float* x      = (const float*)d_in[0];
    const float* ln_g   = (const float*)d_in[1];
    const float* ln_b   = (const float*)d_in[2];
    const float* log_dt = (const float*)d_in[3];
    const float* Alr    = (const float*)d_in[4];
    const float* Aim    = (const float*)d_in[5];
    const float* Bre    = (const float*)d_in[6];
    const float* Bim    = (const float*)d_in[7];
    const float* Cre    = (const float*)d_in[8];
    const float* Cim    = (const float*)d_in[9];
    const float* Dp     = (const float*)d_in[10];
    const float* s4oW   = (const float*)d_in[11];
    const float* s4ob   = (const float*)d_in[12];
    const float* lin1W  = (const float*)d_in[13];
    const float* lin1b  = (const float*)d_in[14];
    const float* lin2W  = (const float*)d_in[15];
    const float* lin2b  = (const float*)d_in[16];
    const float* headW[2] = {(const float*)d_in[17], (const float*)d_in[21]};
    const float* headb[2] = {(const float*)d_in[18], (const float*)d_in[22]};
    const float* projW[2] = {(const float*)d_in[19], (const float*)d_in[23]};
    const float* projb[2] = {(const float*)d_in[20], (const float*)d_in[24]};

    char* w = (char*)d_ws;
    unsigned short* A0 = (unsigned short*)w;  w += (size_t)TOK * DM * 2;
    unsigned short* A1 = (unsigned short*)w;  w += (size_t)TOK * DM * 2;
    unsigned short* A2 = (unsigned short*)w;  w += (size_t)TOK * DM * 2;
    float2* dtA  = (float2*)w;                w += (size_t)NL * DM * NST * 8;
    float2* lam  = (float2*)w;                w += (size_t)NL * DM * NST * 8;
    float2* lamT = (float2*)w;                w += (size_t)NL * DM * NST * 8;
    float2* CB   = (float2*)w;                w += (size_t)NL * DM * NST * 8;
    float2* P    = (float2*)w;                w += (size_t)BSZ * DM * NCH * NST * 8;  // 16 MiB
    float2* Wtab = (float2*)w;                w += (size_t)DM * NST * TC * 8;
    float*  KtabC = (float*)w;                w += (size_t)DM * TC * 4;
    unsigned short* wb = (unsigned short*)w;  w += (size_t)786432 * 2;   // bf16 weights
    if ((size_t)(w - (char*)d_ws) > ws_size) return;   // 46.1 MiB (44.6 proven r16/17)
    unsigned short* F = (unsigned short*)P;   // alias: P dead after layer-1 conv_out

    unsigned short* WB_s4o[2]  = {wb + 0,      wb + 65536};
    unsigned short* WB_lin1[2] = {wb + 131072, wb + 196608};
    unsigned short* WB_lin2[2] = {wb + 262144, wb + 327680};
    unsigned short* WB_head[2] = {wb + 393216, wb + 524288};   // N=256 / N=512
    unsigned short* WB_proj[2] = {wb + 458752, wb + 655360};

    k_setup_modes<<<NL * DM * NST / 256, 256, 0, stream>>>(
        log_dt, Alr, Aim, Bre, Bim, Cre, Cim, dtA, lam, lamT, CB);
    for (int i = 0; i < NL; ++i) {
        size_t wf = (size_t)i * DM * DM;
        k_wcvt<<<256, 256, 0, stream>>>(s4oW + wf,  WB_s4o[i],  DM);
        k_wcvt<<<256, 256, 0, stream>>>(lin1W + wf, WB_lin1[i], DM);
        k_wcvt<<<256, 256, 0, stream>>>(lin2W + wf, WB_lin2[i], DM);
    }
    k_wcvt<<<256, 256, 0, stream>>>(headW[0], WB_head[0], DM);
    k_wcvt<<<256, 256, 0, stream>>>(projW[0], WB_proj[0], DM);
    k_wcvt<<<512, 256, 0, stream>>>(headW[1], WB_head[1], 2 * DM);
    k_wcvt<<<512, 256, 0, stream>>>(projW[1], WB_proj[1], 2 * DM);
    {
        dim3 gt(LSEQ / 32, DM / 32, BSZ);
        dim3 bt(32, 8);
        k_transpose_in<<<gt, bt, 0, stream>>>(x, A0);
    }

    dim3 gg(TOK / 64, DM / 64);
    for (int i = 0; i < NL; ++i) {
        size_t off = (size_t)i * DM * NST;

        k_layernorm<<<TOK, DM, 0, stream>>>(A0, A1, ln_g + (2 * i) * DM,
                                            ln_b + (2 * i) * DM);
        k_setup_wk<<<DM * TC / 128, 128, 0, stream>>>(dtA + off, lam + off,
                                                      CB + off, KtabC, Wtab);
        {
            dim3 gs(NCH, DM / 8, BSZ);
            k_chunk_states<<<gs, 256, 0, stream>>>(A1, lam + off, P);
        }
        k_chunk_scan<<<BSZ * DM * NST / 256, 256, 0, stream>>>(lamT + off, P);
        {
            dim3 gc(NCH, DM);
            k_conv_out<<<gc, 128, 0, stream>>>(A1, KtabC, Wtab, P, Dp + i * DM);
        }
        // A1 @ s4o -> A2 ; A2 @ lin1 + res(A0) -> A1 (= o1)
        k_gemm_mfma<<<gg, 256, 0, stream>>>(A1, WB_s4o[i], s4ob + i * DM, 0, A2, DM, 0);
        k_gemm_mfma<<<gg, 256, 0, stream>>>(A2, WB_lin1[i], lin1b + i * DM, A0, A1, DM, 0);
        // LN2(A1) -> A0 ; gelu(A0 @ lin2) -> A2
        k_layernorm<<<TOK, DM, 0, stream>>>(A1, A0, ln_g + (2 * i + 1) * DM,
                                            ln_b + (2 * i + 1) * DM);
        k_gemm_mfma<<<gg, 256, 0, stream>>>(A0, WB_lin2[i], lin2b + i * DM, 0, A2, DM, 1);
        if (i == 0) {
            // head0: A2 -> A0 ; proj0: A1 accum -> A0. Layer out = A0.
            k_gemm_mfma<<<gg, 256, 0, stream>>>(A2, WB_head[0], headb[0], 0, A0, DM, 0);
            k_gemm_mfma<<<gg, 256, 0, stream>>>(A1, WB_proj[0], projb[0], 0, A0, DM, 2);
        } else {
            dim3 gh(TOK / 64, 2 * DM / 64);
            k_gemm_mfma<<<gh, 256, 0, stream>>>(A2, WB_head[1], headb[1], 0, F, 2 * DM, 0);
            k_gemm_mfma<<<gh, 256, 0, stream>>>(A1, WB_proj[1], projb[1], 0, F, 2 * DM, 2 | 8);
        }
    }
    {
        dim3 gf(LSEQ / 32, 2 * DM / 32, BSZ);
        dim3 bf(32, 8);
        k_final_out<<<gf, bf, 0, stream>>>(F, out);
    }
}

// Round 19
// 571.900 us; speedup vs baseline: 2.3041x; 1.0054x over previous
//
#include <hip/hip_runtime.h>

// S4MaskNet: 2-layer S4, B=8, D=256, L=2048, N=32. Inputs f32, OUTPUT f32.
// r19: (1) Wc = s4oW@lin1W weight fusion (-2 GEMMs); (2) head+proj fused
// K=512 GEMM (-2 GEMMs); (3) h-major uT layout for conv path: LN1 writes
// transposed, chunk_states/conv_out read coalesced; conv_out 4-chunk loop
// amortizes Wtab staging. Buffers rotate in 3x8MiB, ws 46.1 MiB (proven).

#define BSZ 8
#define DM 256
#define LSEQ 2048
#define NST 32
#define TC 64
#define NCH 32
#define TOK (BSZ*LSEQ)
#define NL 2

typedef __attribute__((ext_vector_type(8))) short bf16x8;
typedef __attribute__((ext_vector_type(4))) float f32x4;
typedef unsigned short ushort_t;

__device__ __forceinline__ float b2f(unsigned short v) {
    unsigned int u = ((unsigned int)v) << 16;
    float f;
    __builtin_memcpy(&f, &u, 4);
    return f;
}
__device__ __forceinline__ unsigned short f2b(float f) {
    unsigned int u;
    __builtin_memcpy(&u, &f, 4);
    unsigned int r = (u + 0x7FFFu + ((u >> 16) & 1u)) >> 16;   // RNE
    return (unsigned short)r;
}
__device__ __forceinline__ float gelu_f(float z) {
    float x = z * 0.70710678118654752f;
    float ax = fabsf(x);
    float t = 1.0f / (1.0f + 0.3275911f * ax);
    float poly = t * (0.254829592f + t * (-0.284496736f + t * (1.421413741f +
                 t * (-1.453152027f + t * 1.061405429f))));
    float erfax = 1.0f - poly * expf(-ax * ax);
    float er = (x < 0.0f) ? -erfax : erfax;
    return 0.5f * z * (1.0f + er);
}

// ---- setup: dtA, lambda, lambda^TC, CB ----
__global__ void k_setup_modes(const float* log_dt, const float* Alr, const float* Aim,
                              const float* Bre, const float* Bim,
                              const float* Cre, const float* Cim,
                              float2* dtA, float2* lam, float2* lamT, float2* CB) {
    int idx = blockIdx.x * blockDim.x + threadIdx.x;
    if (idx >= NL * DM * NST) return;
    int h = (idx >> 5) & (DM - 1);
    int i = idx >> 13;
    float dt  = expf(log_dt[i * DM + h]);
    float Are = -expf(Alr[idx]);
    float Ai  = Aim[idx];
    float dr = dt * Are, di = dt * Ai;
    float er = expf(dr);
    float lr = er * cosf(di), li = er * sinf(di);
    float inv = 1.0f / (Are * Are + Ai * Ai);
    float e1r = lr - 1.0f, e1i = li;
    float tr = (e1r * Are + e1i * Ai) * inv;
    float ti = (e1i * Are - e1r * Ai) * inv;
    float br = Bre[idx], bi = Bim[idx];
    float dBr = br * tr - bi * ti, dBi = br * ti + bi * tr;
    float cr = Cre[idx], ci = Cim[idx];
    dtA[idx] = make_float2(dr, di);
    lam[idx] = make_float2(lr, li);
    CB[idx]  = make_float2(cr * dBr - ci * dBi, cr * dBi + ci * dBr);
    float pr = lr, pi = li;
    for (int s = 0; s < 6; ++s) { float nr = pr * pr - pi * pi; pi = 2.f * pr * pi; pr = nr; }
    lamT[idx] = make_float2(pr, pi);
}

// ---- weight convert+transpose: W[k][N] f32 -> WBt[n][256] bf16 ----
__global__ void k_wcvt(const float* src, ushort_t* dst, int N) {
    int idx = blockIdx.x * 256 + threadIdx.x;
    if (idx >= N * 256) return;
    int n = idx >> 8, k = idx & 255;
    dst[idx] = f2b(src[(size_t)k * N + n]);
}

// ---- fused weight: WBc[c][r] = bf16( sum_k s4oW[r,k]*lin1W[k,c] ) ----
__global__ void k_wc_fuse(const float* Wa, const float* Wb, ushort_t* WBc) {
    int c = blockIdx.x;      // 256
    int r = threadIdx.x;     // 256
    const float* ar = Wa + (size_t)r * 256;
    float s = 0.f;
    for (int k = 0; k < 256; ++k) s = fmaf(ar[k], Wb[(size_t)k * 256 + c], s);
    WBc[(size_t)c * 256 + r] = f2b(s);
}
// bc[c] = sum_k s4ob[k]*lin1W[k,c] + lin1b[c]
__global__ void k_bc_fuse(const float* s4ob, const float* Wb, const float* lin1b,
                          float* bc) {
    int c = threadIdx.x;
    float s = lin1b[c];
    for (int k = 0; k < 256; ++k) s = fmaf(s4ob[k], Wb[(size_t)k * 256 + c], s);
    bc[c] = s;
}

// ---- chunk tables ----
__global__ void k_setup_wk(const float2* dtA_l, const float2* lam_l, const float2* CB_l,
                           float* Ktab, float2* Wtab) {
    int idx = blockIdx.x * blockDim.x + threadIdx.x;
    if (idx >= DM * TC) return;
    int t = idx & (TC - 1);
    int h = idx >> 6;
    int base = h * NST;
    float ft = (float)t;
    float Ks = 0.f;
    for (int n = 0; n < NST; ++n) {
        float2 d = dtA_l[base + n]; float2 l1 = lam_l[base + n]; float2 cb = CB_l[base + n];
        float er = expf(d.x * ft);
        float cs = cosf(d.y * ft), sn = sinf(d.y * ft);
        float ltr = er * cs, lti = er * sn;
        Ks += cb.x * ltr - cb.y * lti;
        float p1r = ltr * l1.x - lti * l1.y, p1i = ltr * l1.y + lti * l1.x;
        Wtab[(h * NST + n) * TC + t] =
            make_float2(cb.x * p1r - cb.y * p1i, cb.x * p1i + cb.y * p1r);
    }
    Ktab[idx] = 2.f * Ks;
}

// ---- x [B, D, L] f32 -> o [B, L, D] bf16 ----
__global__ void k_transpose_in(const float* x, ushort_t* o) {
    __shared__ float tile[32][33];
    int b = blockIdx.z;
    int l0 = blockIdx.x * 32, d0 = blockIdx.y * 32;
    int tx = threadIdx.x, ty = threadIdx.y;
    for (int k = 0; k < 4; ++k)
        tile[ty + 8 * k][tx] = x[((size_t)b * DM + d0 + ty + 8 * k) * LSEQ + l0 + tx];
    __syncthreads();
    for (int k = 0; k < 4; ++k)
        o[((size_t)b * LSEQ + l0 + ty + 8 * k) * DM + d0 + tx] = f2b(tile[tx][ty + 8 * k]);
}

// ---- layernorm -> token-major ----
__global__ void k_layernorm(const ushort_t* src, ushort_t* dst,
                            const float* g, const float* bb) {
    __shared__ float r1[DM];
    __shared__ float r2[DM];
    int tok = blockIdx.x;
    int d = threadIdx.x;
    float v = b2f(src[(size_t)tok * DM + d]);
    r1[d] = v;
    r2[d] = v * v;
    __syncthreads();
    for (int s = DM / 2; s > 0; s >>= 1) {
        if (d < s) { r1[d] += r1[d + s]; r2[d] += r2[d + s]; }
        __syncthreads();
    }
    float m = r1[0] * (1.0f / DM);
    float var = r2[0] * (1.0f / DM) - m * m;
    float inv = rsqrtf(var + 1e-5f);
    dst[(size_t)tok * DM + d] = f2b((v - m) * inv * g[d] + bb[d]);
}

// ---- layernorm -> h-major transposed (uT[(b*DM+d)*LSEQ + l]) ----
__global__ void k_layernorm_T(const ushort_t* src, ushort_t* dstT,
                              const float* g, const float* bb) {
    __shared__ float r1[DM];
    __shared__ float r2[DM];
    int tok = blockIdx.x;
    int d = threadIdx.x;
    float v = b2f(src[(size_t)tok * DM + d]);
    r1[d] = v;
    r2[d] = v * v;
    __syncthreads();
    for (int s = DM / 2; s > 0; s >>= 1) {
        if (d < s) { r1[d] += r1[d + s]; r2[d] += r2[d + s]; }
        __syncthreads();
    }
    float m = r1[0] * (1.0f / DM);
    float var = r2[0] * (1.0f / DM) - m * m;
    float inv = rsqrtf(var + 1e-5f);
    int b = tok >> 11, l = tok & 2047;
    dstT[((size_t)b * DM + d) * LSEQ + l] = f2b((v - m) * inv * g[d] + bb[d]);
}

// ---- chunk states from uT (coalesced/broadcast reads) ----
__global__ void k_chunk_states(const ushort_t* uT, const float2* lam_l, float2* P) {
    int n = threadIdx.x & 31, hs = threadIdx.x >> 5;
    int c = blockIdx.x, h = blockIdx.y * 8 + hs, b = blockIdx.z;
    float2 lm = lam_l[h * NST + n];
    float sr = 0.f, si = 0.f;
    const ushort_t* up = uT + ((size_t)b * DM + h) * LSEQ + c * TC;
#pragma unroll 8
    for (int t = 0; t < TC; ++t) {
        float u = b2f(up[t]);
        float nr = fmaf(lm.x, sr, fmaf(-lm.y, si, u));
        float ni = fmaf(lm.x, si, lm.y * sr);
        sr = nr; si = ni;
    }
    P[(((size_t)b * DM + h) * NCH + c) * NST + n] = make_float2(sr, si);
}

// ---- scan ----
__global__ void k_chunk_scan(const float2* lamT_l, float2* P) {
    int idx = blockIdx.x * blockDim.x + threadIdx.x;
    if (idx >= BSZ * DM * NST) return;
    int n = idx & 31, h = (idx >> 5) & 255, b = idx >> 13;
    float2 lT = lamT_l[h * NST + n];
    float hr = 0.f, hi = 0.f;
    float2* base = P + (((size_t)b * DM + h) * NCH) * NST + n;
    for (int c = 0; c < NCH; ++c) {
        float2 p = base[(size_t)c * NST];
        base[(size_t)c * NST] = make_float2(hr, hi);
        float nr = fmaf(lT.x, hr, fmaf(-lT.y, hi, p.x));
        float ni = fmaf(lT.x, hi, fmaf(lT.y, hr, p.y));
        hr = nr; hi = ni;
    }
}

// ---- conv out: reads uT coalesced, writes gelu to G token-major ----
// grid (NCH/4, DM); 4 chunks per block amortize Wtab staging.
__global__ void k_conv_out(const ushort_t* uT, ushort_t* G, const float* Ktab,
                           const float2* Wtab, const float2* S, const float* Dp_l) {
    int h = blockIdx.y;
    int tid = threadIdx.x;                      // 128 = 8b x 16q
    __shared__ float Kch[TC];
    __shared__ float Wre[NST][TC];
    __shared__ float Wim[NST][TC];
    __shared__ float uch[BSZ][TC + 1];
    __shared__ float hre[BSZ][NST + 1];
    __shared__ float him[BSZ][NST + 1];
    if (tid < TC) Kch[tid] = Ktab[h * TC + tid];
    for (int idx = tid; idx < NST * TC; idx += 128) {
        float2 wv = Wtab[(size_t)h * NST * TC + idx];
        Wre[idx >> 6][idx & 63] = wv.x;
        Wim[idx >> 6][idx & 63] = wv.y;
    }
    float dp = Dp_l[h];
    int b = tid >> 4, q = tid & 15, t0 = q * 4;
    for (int cc = 0; cc < 4; ++cc) {
        int c = blockIdx.x * 4 + cc;
        __syncthreads();   // protect prior-iter uch reads / first-iter W stage
        for (int idx = tid; idx < BSZ * TC; idx += 128) {
            int bb = idx >> 6, t = idx & 63;
            uch[bb][t] = b2f(uT[((size_t)bb * DM + h) * LSEQ + c * TC + t]);
        }
        for (int idx = tid; idx < BSZ * NST; idx += 128) {
            int bb = idx >> 5, n = idx & 31;
            float2 hv = S[(((size_t)bb * DM + h) * NCH + c) * NST + n];
            hre[bb][n] = hv.x;
            him[bb][n] = hv.y;
        }
        __syncthreads();
        float s0 = 0, s1 = 0, s2 = 0, s3 = 0;
        float u0 = uch[b][t0], u1 = uch[b][t0 + 1], u2 = uch[b][t0 + 2], u3 = uch[b][t0 + 3];
        for (int d = 0; d <= t0; ++d) {
            float kk = Kch[d];
            s0 = fmaf(kk, u0, s0); s1 = fmaf(kk, u1, s1);
            s2 = fmaf(kk, u2, s2); s3 = fmaf(kk, u3, s3);
            u3 = u2; u2 = u1; u1 = u0;
            u0 = (d < t0) ? uch[b][t0 - d - 1] : 0.f;
        }
        {
            float k1 = Kch[t0 + 1], k2 = Kch[t0 + 2], k3 = Kch[t0 + 3];
            s1 = fmaf(k1, u1, s1); s2 = fmaf(k1, u2, s2); s3 = fmaf(k1, u3, s3);
            s2 = fmaf(k2, u1, s2); s3 = fmaf(k2, u2, s3);
            s3 = fmaf(k3, u1, s3);
        }
        float y0 = 0, y1 = 0, y2 = 0, y3 = 0;
#pragma unroll
        for (int n = 0; n < NST; ++n) {
            float hr = hre[b][n], hi = him[b][n];
            y0 += Wre[n][t0] * hr - Wim[n][t0] * hi;
            y1 += Wre[n][t0 + 1] * hr - Wim[n][t0 + 1] * hi;
            y2 += Wre[n][t0 + 2] * hr - Wim[n][t0 + 2] * hi;
            y3 += Wre[n][t0 + 3] * hr - Wim[n][t0 + 3] * hi;
        }
        size_t obase = ((size_t)b * LSEQ + c * TC + t0) * DM + h;
        float z;
        z = s0 + 2.f * y0 + dp * uch[b][t0];     G[obase]          = f2b(gelu_f(z));
        z = s1 + 2.f * y1 + dp * uch[b][t0 + 1]; G[obase + DM]     = f2b(gelu_f(z));
        z = s2 + 2.f * y2 + dp * uch[b][t0 + 2]; G[obase + 2 * DM] = f2b(gelu_f(z));
        z = s3 + 2.f * y3 + dp * uch[b][t0 + 3]; G[obase + 3 * DM] = f2b(gelu_f(z));
    }
}

// ---- MFMA GEMM: C[M,N](bf16) = A[TOK,256](bf16) @ WBt^T + bias ----
__global__ void k_gemm_mfma(const ushort_t* A, const ushort_t* WBt,
                            const float* bias, const ushort_t* res,
                            ushort_t* C, int N, int flags) {
    int m0 = blockIdx.x * 64, n0 = blockIdx.y * 64;
    int tid = threadIdx.x;
    int wv = tid >> 6, l = tid & 63;
    int lr = l & 15, lk = (l >> 4) * 8;
    f32x4 acc0 = {0.f, 0.f, 0.f, 0.f};
    f32x4 acc1 = acc0, acc2 = acc0, acc3 = acc0;
    const ushort_t* arow = A + (size_t)(m0 + wv * 16 + lr) * 256 + lk;
    const ushort_t* bcol = WBt + (size_t)(n0 + lr) * 256 + lk;
#pragma unroll
    for (int k0 = 0; k0 < 256; k0 += 32) {
        bf16x8 a  = *(const bf16x8*)(arow + k0);
        bf16x8 b0 = *(const bf16x8*)(bcol + k0);
        bf16x8 b1 = *(const bf16x8*)(bcol + 16 * 256 + k0);
        bf16x8 b2 = *(const bf16x8*)(bcol + 32 * 256 + k0);
        bf16x8 b3 = *(const bf16x8*)(bcol + 48 * 256 + k0);
        acc0 = __builtin_amdgcn_mfma_f32_16x16x32_bf16(a, b0, acc0, 0, 0, 0);
        acc1 = __builtin_amdgcn_mfma_f32_16x16x32_bf16(a, b1, acc1, 0, 0, 0);
        acc2 = __builtin_amdgcn_mfma_f32_16x16x32_bf16(a, b2, acc2, 0, 0, 0);
        acc3 = __builtin_amdgcn_mfma_f32_16x16x32_bf16(a, b3, acc3, 0, 0, 0);
    }
    int em = m0 + wv * 16 + (l >> 4) * 4;
    int en = n0 + (l & 15);
    f32x4 accs[4] = {acc0, acc1, acc2, acc3};
#pragma unroll
    for (int nt = 0; nt < 4; ++nt) {
        int n = en + nt * 16;
        float bsv = bias[n];
#pragma unroll
        for (int r = 0; r < 4; ++r) {
            int m = em + r;
            float v = accs[nt][r] + bsv;
            if (res) v += b2f(res[(size_t)m * DM + n]);
            size_t idx = (size_t)m * N + n;
            if (flags & 1) v = gelu_f(v);
            if (flags & 8) v = fmaxf(v, 0.0f);
            C[idx] = f2b(v);
        }
    }
}

// ---- fused two-operand MFMA GEMM: C = Aa@WBa^T + Ab@WBb^T + biasA + biasB ----
__global__ void k_gemm2_mfma(const ushort_t* Aa, const ushort_t* WBa,
                             const ushort_t* Ab, const ushort_t* WBb,
                             const float* biasA, const float* biasB,
                             ushort_t* C, int N, int flags) {
    int m0 = blockIdx.x * 64, n0 = blockIdx.y * 64;
    int tid = threadIdx.x;
    int wv = tid >> 6, l = tid & 63;
    int lr = l & 15, lk = (l >> 4) * 8;
    f32x4 acc0 = {0.f, 0.f, 0.f, 0.f};
    f32x4 acc1 = acc0, acc2 = acc0, acc3 = acc0;
    {
        const ushort_t* arow = Aa + (size_t)(m0 + wv * 16 + lr) * 256 + lk;
        const ushort_t* bcol = WBa + (size_t)(n0 + lr) * 256 + lk;
#pragma unroll
        for (int k0 = 0; k0 < 256; k0 += 32) {
            bf16x8 a  = *(const bf16x8*)(arow + k0);
            bf16x8 b0 = *(const bf16x8*)(bcol + k0);
            bf16x8 b1 = *(const bf16x8*)(bcol + 16 * 256 + k0);
            bf16x8 b2 = *(const bf16x8*)(bcol + 32 * 256 + k0);
            bf16x8 b3 = *(const bf16x8*)(bcol + 48 * 256 + k0);
            acc0 = __builtin_amdgcn_mfma_f32_16x16x32_bf16(a, b0, acc0, 0, 0, 0);
            acc1 = __builtin_amdgcn_mfma_f32_16x16x32_bf16(a, b1, acc1, 0, 0, 0);
            acc2 = __builtin_amdgcn_mfma_f32_16x16x32_bf16(a, b2, acc2, 0, 0, 0);
            acc3 = __builtin_amdgcn_mfma_f32_16x16x32_bf16(a, b3, acc3, 0, 0, 0);
        }
    }
    {
        const ushort_t* arow = Ab + (size_t)(m0 + wv * 16 + lr) * 256 + lk;
        const ushort_t* bcol = WBb + (size_t)(n0 + lr) * 256 + lk;
#pragma unroll
        for (int k0 = 0; k0 < 256; k0 += 32) {
            bf16x8 a  = *(const bf16x8*)(arow + k0);
            bf16x8 b0 = *(const bf16x8*)(bcol + k0);
            bf16x8 b1 = *(const bf16x8*)(bcol + 16 * 256 + k0);
            bf16x8 b2 = *(const bf16x8*)(bcol + 32 * 256 + k0);
            bf16x8 b3 = *(const bf16x8*)(bcol + 48 * 256 + k0);
            acc0 = __builtin_amdgcn_mfma_f32_16x16x32_bf16(a, b0, acc0, 0, 0, 0);
            acc1 = __builtin_amdgcn_mfma_f32_16x16x32_bf16(a, b1, acc1, 0, 0, 0);
            acc2 = __builtin_amdgcn_mfma_f32_16x16x32_bf16(a, b2, acc2, 0, 0, 0);
            acc3 = __builtin_amdgcn_mfma_f32_16x16x32_bf16(a, b3, acc3, 0, 0, 0);
        }
    }
    int em = m0 + wv * 16 + (l >> 4) * 4;
    int en = n0 + (l & 15);
    f32x4 accs[4] = {acc0, acc1, acc2, acc3};
#pragma unroll
    for (int nt = 0; nt < 4; ++nt) {
        int n = en + nt * 16;
        float bsv = biasA[n] + biasB[n];
#pragma unroll
        for (int r = 0; r < 4; ++r) {
            int m = em + r;
            float v = accs[nt][r] + bsv;
            if (flags & 8) v = fmaxf(v, 0.0f);
            C[(size_t)m * N + n] = f2b(v);
        }
    }
}

// ---- final: F [B,L,512] bf16 -> out [2,B,256,L] f32 ----
__global__ void k_final_out(const ushort_t* F, float* out) {
    __shared__ float tile[32][33];
    int b = blockIdx.z;
    int l0 = blockIdx.x * 32, c0 = blockIdx.y * 32;
    int tx = threadIdx.x, ty = threadIdx.y;
    for (int k = 0; k < 4; ++k)
        tile[ty + 8 * k][tx] = b2f(F[((size_t)(b * LSEQ + l0 + ty + 8 * k)) * 512 + c0 + tx]);
    __syncthreads();
    for (int k = 0; k < 4; ++k) {
        int cg = c0 + ty + 8 * k;
        int s = cg >> 8, cc = cg & 255;
        out[(((size_t)s * BSZ + b) * DM + cc) * LSEQ + l0 + tx] = tile[tx][ty + 8 * k];
    }
}

// ---- launcher ----
extern "C" void kernel_launch(void* const* d_in, const int* in_sizes, int n_in,
                              void* d_out, int out_size, void* d_ws, size_t ws_size,
                              hipStream_t stream) {
    (void)in_sizes; (void)n_in; (void)out_size;
    float* out = (float*)d_out;

    const float* x      = (const float*)d_in[0];
    const float* ln_g   = (const float*)d_in[1];
    const float* ln_b   = (const float*)d_in[2];
    const float* log_dt = (const float*)d_in[3];
    const float* Alr    = (const float*)d_in[4];
    const float* Aim    = (const float*)d_in[5];
    const float* Bre    = (const float*)d_in[6];
    const float* Bim    = (const float*)d_in[7];
    const float* Cre    = (const float*)d_in[8];
    const float* Cim    = (const float*)d_in[9];
    const float* Dp     = (const float*)d_in[10];
    const float* s4oW   = (const float*)d_in[11];
    const float* s4ob   = (const float*)d_in[12];
    const float* lin1W  = (const float*)d_in[13];
    const float* lin1b  = (const float*)d_in[14];
    const float* lin2W  = (const float*)d_in[15];
    const float* lin2b  = (const float*)d_in[16];
    const float* headW[2] = {(const float*)d_in[17], (const float*)d_in[21]};
    const float* headb[2] = {(const float*)d_in[18], (const float*)d_in[22]};
    const float* projW[2] = {(const float*)d_in[19], (const float*)d_in[23]};
    const float* projb[2] = {(const float*)d_in[20], (const float*)d_in[24]};

    char* w = (char*)d_ws;
    ushort_t* A0 = (ushort_t*)w;  w += (size_t)TOK * DM * 2;
    ushort_t* A1 = (ushort_t*)w;  w += (size_t)TOK * DM * 2;
    ushort_t* A2 = (ushort_t*)w;  w += (size_t)TOK * DM * 2;
    float2* dtA  = (float2*)w;    w += (size_t)NL * DM * NST * 8;
    float2* lam  = (float2*)w;    w += (size_t)NL * DM * NST * 8;
    float2* lamT = (float2*)w;    w += (size_t)NL * DM * NST * 8;
    float2* CB   = (float2*)w;    w += (size_t)NL * DM * NST * 8;
    float2* P    = (float2*)w;    w += (size_t)BSZ * DM * NCH * NST * 8;  // 16 MiB
    float2* Wtab = (float2*)w;    w += (size_t)DM * NST * TC * 8;
    float*  KtabC = (float*)w;    w += (size_t)DM * TC * 4;
    ushort_t* wb = (ushort_t*)w;  w += (size_t)655360 * 2;
    float*  bc   = (float*)w;     w += 512 * 4;
    if ((size_t)(w - (char*)d_ws) > ws_size) return;   // ~46 MiB (proven r18)
    ushort_t* F = (ushort_t*)P;   // alias: P dead after layer-1 conv_out

    ushort_t* WB_lin2[2] = {wb + 0,      wb + 65536};
    ushort_t* WB_head0   = wb + 131072;
    ushort_t* WB_proj0   = wb + 196608;
    ushort_t* WB_head1   = wb + 262144;   // 131072
    ushort_t* WB_proj1   = wb + 393216;   // 131072
    ushort_t* WBc[2]     = {wb + 524288, wb + 589824};

    k_setup_modes<<<NL * DM * NST / 256, 256, 0, stream>>>(
        log_dt, Alr, Aim, Bre, Bim, Cre, Cim, dtA, lam, lamT, CB);
    for (int i = 0; i < NL; ++i) {
        size_t wf = (size_t)i * DM * DM;
        k_wcvt<<<256, 256, 0, stream>>>(lin2W + wf, WB_lin2[i], DM);
        k_wc_fuse<<<256, 256, 0, stream>>>(s4oW + wf, lin1W + wf, WBc[i]);
        k_bc_fuse<<<1, 256, 0, stream>>>(s4ob + i * DM, lin1W + wf, lin1b + i * DM,
                                         bc + i * 256);
    }
    k_wcvt<<<256, 256, 0, stream>>>(headW[0], WB_head0, DM);
    k_wcvt<<<256, 256, 0, stream>>>(projW[0], WB_proj0, DM);
    k_wcvt<<<512, 256, 0, stream>>>(headW[1], WB_head1, 2 * DM);
    k_wcvt<<<512, 256, 0, stream>>>(projW[1], WB_proj1, 2 * DM);
    {
        dim3 gt(LSEQ / 32, DM / 32, BSZ);
        dim3 bt(32, 8);
        k_transpose_in<<<gt, bt, 0, stream>>>(x, A0);
    }

    dim3 gg(TOK / 64, DM / 64);
    for (int i = 0; i < NL; ++i) {
        // rotation: layer0 U=A0,T=A1,G=A2 ; layer1 U=A2,T=A0,G=A1
        ushort_t* U = (i == 0) ? A0 : A2;
        ushort_t* T = (i == 0) ? A1 : A0;
        ushort_t* G = (i == 0) ? A2 : A1;
        size_t off = (size_t)i * DM * NST;

        k_layernorm_T<<<TOK, DM, 0, stream>>>(U, T, ln_g + (2 * i) * DM,
                                              ln_b + (2 * i) * DM);
        k_setup_wk<<<DM * TC / 128, 128, 0, stream>>>(dtA + off, lam + off,
                                                      CB + off, KtabC, Wtab);
        {
            dim3 gs(NCH, DM / 8, BSZ);
            k_chunk_states<<<gs, 256, 0, stream>>>(T, lam + off, P);
        }
        k_chunk_scan<<<BSZ * DM * NST / 256, 256, 0, stream>>>(lamT + off, P);
        {
            dim3 gc(NCH / 4, DM);
            k_conv_out<<<gc, 128, 0, stream>>>(T, G, KtabC, Wtab, P, Dp + i * DM);
        }
        // o1 = G@Wc + bc + U   -> T (uT dead)
        k_gemm_mfma<<<gg, 256, 0, stream>>>(G, WBc[i], bc + i * 256, U, T, DM, 0);
        // LN2(o1=T) -> G (gelu-conv dead)
        k_layernorm<<<TOK, DM, 0, stream>>>(T, G, ln_g + (2 * i + 1) * DM,
                                            ln_b + (2 * i + 1) * DM);
        // g2 = gelu(G@lin2) -> U (residual consumed)
        k_gemm_mfma<<<gg, 256, 0, stream>>>(G, WB_lin2[i], lin2b + i * DM, 0, U, DM, 1);
        if (i == 0) {
            // out = g2@head + o1@proj -> A2 (LN2 buffer dead) = next-layer U
            k_gemm2_mfma<<<gg, 256, 0, stream>>>(U, WB_head0, T, WB_proj0,
                                                 headb[0], projb[0], A2, DM, 0);
        } else {
            dim3 gh(TOK / 64, 2 * DM / 64);
            k_gemm2_mfma<<<gh, 256, 0, stream>>>(U, WB_head1, T, WB_proj1,
                                                 headb[1], projb[1], F, 2 * DM, 8);
        }
    }
    {
        dim3 gf(LSEQ / 32, 2 * DM / 32, BSZ);
        dim3 bf(32, 8);
        k_final_out<<<gf, bf, 0, stream>>>(F, out);
    }
}

// Round 20
// 504.679 us; speedup vs baseline: 2.6110x; 1.1332x over previous
//
#include <hip/hip_runtime.h>

// S4MaskNet: 2-layer S4, B=8, D=256, L=2048, N=32. Inputs f32, OUTPUT f32.
// r20: GEMMs rebuilt as LDS-staged MFMA (coalesced stage + T2 XOR swizzle +
// ds_read_b128 fragments). r19's direct-global MFMA was latency-bound
// (MfmaUtil 4%, 77us). Pipeline/rotation unchanged from r19.

#define BSZ 8
#define DM 256
#define LSEQ 2048
#define NST 32
#define TC 64
#define NCH 32
#define TOK (BSZ*LSEQ)
#define NL 2

typedef __attribute__((ext_vector_type(8))) short bf16x8;
typedef __attribute__((ext_vector_type(4))) float f32x4;
typedef unsigned short ushort_t;

__device__ __forceinline__ float b2f(unsigned short v) {
    unsigned int u = ((unsigned int)v) << 16;
    float f;
    __builtin_memcpy(&f, &u, 4);
    return f;
}
__device__ __forceinline__ unsigned short f2b(float f) {
    unsigned int u;
    __builtin_memcpy(&u, &f, 4);
    unsigned int r = (u + 0x7FFFu + ((u >> 16) & 1u)) >> 16;   // RNE
    return (unsigned short)r;
}
__device__ __forceinline__ float gelu_f(float z) {
    float x = z * 0.70710678118654752f;
    float ax = fabsf(x);
    float t = 1.0f / (1.0f + 0.3275911f * ax);
    float poly = t * (0.254829592f + t * (-0.284496736f + t * (1.421413741f +
                 t * (-1.453152027f + t * 1.061405429f))));
    float erfax = 1.0f - poly * expf(-ax * ax);
    float er = (x < 0.0f) ? -erfax : erfax;
    return 0.5f * z * (1.0f + er);
}

// ---- setup: dtA, lambda, lambda^TC, CB ----
__global__ void k_setup_modes(const float* log_dt, const float* Alr, const float* Aim,
                              const float* Bre, const float* Bim,
                              const float* Cre, const float* Cim,
                              float2* dtA, float2* lam, float2* lamT, float2* CB) {
    int idx = blockIdx.x * blockDim.x + threadIdx.x;
    if (idx >= NL * DM * NST) return;
    int h = (idx >> 5) & (DM - 1);
    int i = idx >> 13;
    float dt  = expf(log_dt[i * DM + h]);
    float Are = -expf(Alr[idx]);
    float Ai  = Aim[idx];
    float dr = dt * Are, di = dt * Ai;
    float er = expf(dr);
    float lr = er * cosf(di), li = er * sinf(di);
    float inv = 1.0f / (Are * Are + Ai * Ai);
    float e1r = lr - 1.0f, e1i = li;
    float tr = (e1r * Are + e1i * Ai) * inv;
    float ti = (e1i * Are - e1r * Ai) * inv;
    float br = Bre[idx], bi = Bim[idx];
    float dBr = br * tr - bi * ti, dBi = br * ti + bi * tr;
    float cr = Cre[idx], ci = Cim[idx];
    dtA[idx] = make_float2(dr, di);
    lam[idx] = make_float2(lr, li);
    CB[idx]  = make_float2(cr * dBr - ci * dBi, cr * dBi + ci * dBr);
    float pr = lr, pi = li;
    for (int s = 0; s < 6; ++s) { float nr = pr * pr - pi * pi; pi = 2.f * pr * pi; pr = nr; }
    lamT[idx] = make_float2(pr, pi);
}

// ---- weight convert+transpose: W[k][N] f32 -> WBt[n][256] bf16 ----
__global__ void k_wcvt(const float* src, ushort_t* dst, int N) {
    int idx = blockIdx.x * 256 + threadIdx.x;
    if (idx >= N * 256) return;
    int n = idx >> 8, k = idx & 255;
    dst[idx] = f2b(src[(size_t)k * N + n]);
}

// ---- fused weight: WBc[c][r] = bf16( sum_k s4oW[r,k]*lin1W[k,c] ) ----
__global__ void k_wc_fuse(const float* Wa, const float* Wb, ushort_t* WBc) {
    int c = blockIdx.x;
    int r = threadIdx.x;
    const float* ar = Wa + (size_t)r * 256;
    float s = 0.f;
    for (int k = 0; k < 256; ++k) s = fmaf(ar[k], Wb[(size_t)k * 256 + c], s);
    WBc[(size_t)c * 256 + r] = f2b(s);
}
__global__ void k_bc_fuse(const float* s4ob, const float* Wb, const float* lin1b,
                          float* bc) {
    int c = threadIdx.x;
    float s = lin1b[c];
    for (int k = 0; k < 256; ++k) s = fmaf(s4ob[k], Wb[(size_t)k * 256 + c], s);
    bc[c] = s;
}

// ---- chunk tables ----
__global__ void k_setup_wk(const float2* dtA_l, const float2* lam_l, const float2* CB_l,
                           float* Ktab, float2* Wtab) {
    int idx = blockIdx.x * blockDim.x + threadIdx.x;
    if (idx >= DM * TC) return;
    int t = idx & (TC - 1);
    int h = idx >> 6;
    int base = h * NST;
    float ft = (float)t;
    float Ks = 0.f;
    for (int n = 0; n < NST; ++n) {
        float2 d = dtA_l[base + n]; float2 l1 = lam_l[base + n]; float2 cb = CB_l[base + n];
        float er = expf(d.x * ft);
        float cs = cosf(d.y * ft), sn = sinf(d.y * ft);
        float ltr = er * cs, lti = er * sn;
        Ks += cb.x * ltr - cb.y * lti;
        float p1r = ltr * l1.x - lti * l1.y, p1i = ltr * l1.y + lti * l1.x;
        Wtab[(h * NST + n) * TC + t] =
            make_float2(cb.x * p1r - cb.y * p1i, cb.x * p1i + cb.y * p1r);
    }
    Ktab[idx] = 2.f * Ks;
}

// ---- x [B, D, L] f32 -> o [B, L, D] bf16 ----
__global__ void k_transpose_in(const float* x, ushort_t* o) {
    __shared__ float tile[32][33];
    int b = blockIdx.z;
    int l0 = blockIdx.x * 32, d0 = blockIdx.y * 32;
    int tx = threadIdx.x, ty = threadIdx.y;
    for (int k = 0; k < 4; ++k)
        tile[ty + 8 * k][tx] = x[((size_t)b * DM + d0 + ty + 8 * k) * LSEQ + l0 + tx];
    __syncthreads();
    for (int k = 0; k < 4; ++k)
        o[((size_t)b * LSEQ + l0 + ty + 8 * k) * DM + d0 + tx] = f2b(tile[tx][ty + 8 * k]);
}

// ---- layernorm -> token-major ----
__global__ void k_layernorm(const ushort_t* src, ushort_t* dst,
                            const float* g, const float* bb) {
    __shared__ float r1[DM];
    __shared__ float r2[DM];
    int tok = blockIdx.x;
    int d = threadIdx.x;
    float v = b2f(src[(size_t)tok * DM + d]);
    r1[d] = v;
    r2[d] = v * v;
    __syncthreads();
    for (int s = DM / 2; s > 0; s >>= 1) {
        if (d < s) { r1[d] += r1[d + s]; r2[d] += r2[d + s]; }
        __syncthreads();
    }
    float m = r1[0] * (1.0f / DM);
    float var = r2[0] * (1.0f / DM) - m * m;
    float inv = rsqrtf(var + 1e-5f);
    dst[(size_t)tok * DM + d] = f2b((v - m) * inv * g[d] + bb[d]);
}

// ---- layernorm -> h-major transposed ----
__global__ void k_layernorm_T(const ushort_t* src, ushort_t* dstT,
                              const float* g, const float* bb) {
    __shared__ float r1[DM];
    __shared__ float r2[DM];
    int tok = blockIdx.x;
    int d = threadIdx.x;
    float v = b2f(src[(size_t)tok * DM + d]);
    r1[d] = v;
    r2[d] = v * v;
    __syncthreads();
    for (int s = DM / 2; s > 0; s >>= 1) {
        if (d < s) { r1[d] += r1[d + s]; r2[d] += r2[d + s]; }
        __syncthreads();
    }
    float m = r1[0] * (1.0f / DM);
    float var = r2[0] * (1.0f / DM) - m * m;
    float inv = rsqrtf(var + 1e-5f);
    int b = tok >> 11, l = tok & 2047;
    dstT[((size_t)b * DM + d) * LSEQ + l] = f2b((v - m) * inv * g[d] + bb[d]);
}

// ---- chunk states from uT ----
__global__ void k_chunk_states(const ushort_t* uT, const float2* lam_l, float2* P) {
    int n = threadIdx.x & 31, hs = threadIdx.x >> 5;
    int c = blockIdx.x, h = blockIdx.y * 8 + hs, b = blockIdx.z;
    float2 lm = lam_l[h * NST + n];
    float sr = 0.f, si = 0.f;
    const ushort_t* up = uT + ((size_t)b * DM + h) * LSEQ + c * TC;
#pragma unroll 8
    for (int t = 0; t < TC; ++t) {
        float u = b2f(up[t]);
        float nr = fmaf(lm.x, sr, fmaf(-lm.y, si, u));
        float ni = fmaf(lm.x, si, lm.y * sr);
        sr = nr; si = ni;
    }
    P[(((size_t)b * DM + h) * NCH + c) * NST + n] = make_float2(sr, si);
}

// ---- scan ----
__global__ void k_chunk_scan(const float2* lamT_l, float2* P) {
    int idx = blockIdx.x * blockDim.x + threadIdx.x;
    if (idx >= BSZ * DM * NST) return;
    int n = idx & 31, h = (idx >> 5) & 255, b = idx >> 13;
    float2 lT = lamT_l[h * NST + n];
    float hr = 0.f, hi = 0.f;
    float2* base = P + (((size_t)b * DM + h) * NCH) * NST + n;
    for (int c = 0; c < NCH; ++c) {
        float2 p = base[(size_t)c * NST];
        base[(size_t)c * NST] = make_float2(hr, hi);
        float nr = fmaf(lT.x, hr, fmaf(-lT.y, hi, p.x));
        float ni = fmaf(lT.x, hi, fmaf(lT.y, hr, p.y));
        hr = nr; hi = ni;
    }
}

// ---- conv out ----
__global__ void k_conv_out(const ushort_t* uT, ushort_t* G, const float* Ktab,
                           const float2* Wtab, const float2* S, const float* Dp_l) {
    int h = blockIdx.y;
    int tid = threadIdx.x;
    __shared__ float Kch[TC];
    __shared__ float Wre[NST][TC];
    __shared__ float Wim[NST][TC];
    __shared__ float uch[BSZ][TC + 1];
    __shared__ float hre[BSZ][NST + 1];
    __shared__ float him[BSZ][NST + 1];
    if (tid < TC) Kch[tid] = Ktab[h * TC + tid];
    for (int idx = tid; idx < NST * TC; idx += 128) {
        float2 wv = Wtab[(size_t)h * NST * TC + idx];
        Wre[idx >> 6][idx & 63] = wv.x;
        Wim[idx >> 6][idx & 63] = wv.y;
    }
    float dp = Dp_l[h];
    int b = tid >> 4, q = tid & 15, t0 = q * 4;
    for (int cc = 0; cc < 4; ++cc) {
        int c = blockIdx.x * 4 + cc;
        __syncthreads();
        for (int idx = tid; idx < BSZ * TC; idx += 128) {
            int bb = idx >> 6, t = idx & 63;
            uch[bb][t] = b2f(uT[((size_t)bb * DM + h) * LSEQ + c * TC + t]);
        }
        for (int idx = tid; idx < BSZ * NST; idx += 128) {
            int bb = idx >> 5, n = idx & 31;
            float2 hv = S[(((size_t)bb * DM + h) * NCH + c) * NST + n];
            hre[bb][n] = hv.x;
            him[bb][n] = hv.y;
        }
        __syncthreads();
        float s0 = 0, s1 = 0, s2 = 0, s3 = 0;
        float u0 = uch[b][t0], u1 = uch[b][t0 + 1], u2 = uch[b][t0 + 2], u3 = uch[b][t0 + 3];
        for (int d = 0; d <= t0; ++d) {
            float kk = Kch[d];
            s0 = fmaf(kk, u0, s0); s1 = fmaf(kk, u1, s1);
            s2 = fmaf(kk, u2, s2); s3 = fmaf(kk, u3, s3);
            u3 = u2; u2 = u1; u1 = u0;
            u0 = (d < t0) ? uch[b][t0 - d - 1] : 0.f;
        }
        {
            float k1 = Kch[t0 + 1], k2 = Kch[t0 + 2], k3 = Kch[t0 + 3];
            s1 = fmaf(k1, u1, s1); s2 = fmaf(k1, u2, s2); s3 = fmaf(k1, u3, s3);
            s2 = fmaf(k2, u1, s2); s3 = fmaf(k2, u2, s3);
            s3 = fmaf(k3, u1, s3);
        }
        float y0 = 0, y1 = 0, y2 = 0, y3 = 0;
#pragma unroll
        for (int n = 0; n < NST; ++n) {
            float hr = hre[b][n], hi = him[b][n];
            y0 += Wre[n][t0] * hr - Wim[n][t0] * hi;
            y1 += Wre[n][t0 + 1] * hr - Wim[n][t0 + 1] * hi;
            y2 += Wre[n][t0 + 2] * hr - Wim[n][t0 + 2] * hi;
            y3 += Wre[n][t0 + 3] * hr - Wim[n][t0 + 3] * hi;
        }
        size_t obase = ((size_t)b * LSEQ + c * TC + t0) * DM + h;
        float z;
        z = s0 + 2.f * y0 + dp * uch[b][t0];     G[obase]          = f2b(gelu_f(z));
        z = s1 + 2.f * y1 + dp * uch[b][t0 + 1]; G[obase + DM]     = f2b(gelu_f(z));
        z = s2 + 2.f * y2 + dp * uch[b][t0 + 2]; G[obase + 2 * DM] = f2b(gelu_f(z));
        z = s3 + 2.f * y3 + dp * uch[b][t0 + 3]; G[obase + 3 * DM] = f2b(gelu_f(z));
    }
}

// ==== LDS-staged MFMA GEMM machinery ====
// Tile 64(M)x64(N), K=256 per phase. XOR swizzle: elem col ^= (row&7)<<3.
__device__ __forceinline__ void stage_tile(const ushort_t* src, int row0,
                                           ushort_t (*dst)[256], int tid) {
    for (int idx = tid; idx < 64 * 32; idx += 256) {
        int r = idx >> 5, ch = (idx & 31) * 8;
        bf16x8 v = *(const bf16x8*)(src + (size_t)(row0 + r) * 256 + ch);
        *(bf16x8*)(&dst[r][ch ^ ((r & 7) << 3)]) = v;
    }
}
__device__ __forceinline__ void mma_tile(const ushort_t (*As)[256],
                                         const ushort_t (*Bs)[256],
                                         int wv, int l, f32x4* acc) {
    int lr = l & 15, lk = (l >> 4) * 8;
    int ax = (lr & 7) << 3;
#pragma unroll
    for (int k0 = 0; k0 < 256; k0 += 32) {
        bf16x8 a  = *(const bf16x8*)(&As[wv * 16 + lr][(lk + k0) ^ ax]);
        bf16x8 b0 = *(const bf16x8*)(&Bs[lr]          [(lk + k0) ^ ax]);
        bf16x8 b1 = *(const bf16x8*)(&Bs[16 + lr]     [(lk + k0) ^ ax]);
        bf16x8 b2 = *(const bf16x8*)(&Bs[32 + lr]     [(lk + k0) ^ ax]);
        bf16x8 b3 = *(const bf16x8*)(&Bs[48 + lr]     [(lk + k0) ^ ax]);
        acc[0] = __builtin_amdgcn_mfma_f32_16x16x32_bf16(a, b0, acc[0], 0, 0, 0);
        acc[1] = __builtin_amdgcn_mfma_f32_16x16x32_bf16(a, b1, acc[1], 0, 0, 0);
        acc[2] = __builtin_amdgcn_mfma_f32_16x16x32_bf16(a, b2, acc[2], 0, 0, 0);
        acc[3] = __builtin_amdgcn_mfma_f32_16x16x32_bf16(a, b3, acc[3], 0, 0, 0);
    }
}

// ---- single: C[M,N] = A @ WBt^T + bias (+res) (gelu/relu flags) ----
__global__ void k_gemm_mfma(const ushort_t* A, const ushort_t* WBt,
                            const float* bias, const ushort_t* res,
                            ushort_t* C, int N, int flags) {
    __shared__ ushort_t As[64][256];
    __shared__ ushort_t Bs[64][256];
    int m0 = blockIdx.x * 64, n0 = blockIdx.y * 64;
    int tid = threadIdx.x;
    int wv = tid >> 6, l = tid & 63;
    stage_tile(A, m0, As, tid);
    stage_tile(WBt, n0, Bs, tid);
    __syncthreads();
    f32x4 acc[4] = {{0,0,0,0},{0,0,0,0},{0,0,0,0},{0,0,0,0}};
    mma_tile(As, Bs, wv, l, acc);
    int em = m0 + wv * 16 + (l >> 4) * 4;
    int en = n0 + (l & 15);
#pragma unroll
    for (int nt = 0; nt < 4; ++nt) {
        int n = en + nt * 16;
        float bsv = bias[n];
#pragma unroll
        for (int r = 0; r < 4; ++r) {
            int m = em + r;
            float v = acc[nt][r] + bsv;
            if (res) v += b2f(res[(size_t)m * DM + n]);
            if (flags & 1) v = gelu_f(v);
            if (flags & 8) v = fmaxf(v, 0.0f);
            C[(size_t)m * N + n] = f2b(v);
        }
    }
}

// ---- fused two-operand: C = Aa@WBa^T + Ab@WBb^T + biasA + biasB ----
__global__ void k_gemm2_mfma(const ushort_t* Aa, const ushort_t* WBa,
                             const ushort_t* Ab, const ushort_t* WBb,
                             const float* biasA, const float* biasB,
                             ushort_t* C, int N, int flags) {
    __shared__ ushort_t As[64][256];
    __shared__ ushort_t Bs[64][256];
    int m0 = blockIdx.x * 64, n0 = blockIdx.y * 64;
    int tid = threadIdx.x;
    int wv = tid >> 6, l = tid & 63;
    f32x4 acc[4] = {{0,0,0,0},{0,0,0,0},{0,0,0,0},{0,0,0,0}};
    stage_tile(Aa, m0, As, tid);
    stage_tile(WBa, n0, Bs, tid);
    __syncthreads();
    mma_tile(As, Bs, wv, l, acc);
    __syncthreads();                 // all reads done before restage
    stage_tile(Ab, m0, As, tid);
    stage_tile(WBb, n0, Bs, tid);
    __syncthreads();
    mma_tile(As, Bs, wv, l, acc);
    int em = m0 + wv * 16 + (l >> 4) * 4;
    int en = n0 + (l & 15);
#pragma unroll
    for (int nt = 0; nt < 4; ++nt) {
        int n = en + nt * 16;
        float bsv = biasA[n] + biasB[n];
#pragma unroll
        for (int r = 0; r < 4; ++r) {
            int m = em + r;
            float v = acc[nt][r] + bsv;
            if (flags & 8) v = fmaxf(v, 0.0f);
            C[(size_t)m * N + n] = f2b(v);
        }
    }
}

// ---- final: F [B,L,512] bf16 -> out [2,B,256,L] f32 ----
__global__ void k_final_out(const ushort_t* F, float* out) {
    __shared__ float tile[32][33];
    int b = blockIdx.z;
    int l0 = blockIdx.x * 32, c0 = blockIdx.y * 32;
    int tx = threadIdx.x, ty = threadIdx.y;
    for (int k = 0; k < 4; ++k)
        tile[ty + 8 * k][tx] = b2f(F[((size_t)(b * LSEQ + l0 + ty + 8 * k)) * 512 + c0 + tx]);
    __syncthreads();
    for (int k = 0; k < 4; ++k) {
        int cg = c0 + ty + 8 * k;
        int s = cg >> 8, cc = cg & 255;
        out[(((size_t)s * BSZ + b) * DM + cc) * LSEQ + l0 + tx] = tile[tx][ty + 8 * k];
    }
}

// ---- launcher ----
extern "C" void kernel_launch(void* const* d_in, const int* in_sizes, int n_in,
                              void* d_out, int out_size, void* d_ws, size_t ws_size,
                              hipStream_t stream) {
    (void)in_sizes; (void)n_in; (void)out_size;
    float* out = (float*)d_out;

    const float* x      = (const float*)d_in[0];
    const float* ln_g   = (const float*)d_in[1];
    const float* ln_b   = (const float*)d_in[2];
    const float* log_dt = (const float*)d_in[3];
    const float* Alr    = (const float*)d_in[4];
    const float* Aim    = (const float*)d_in[5];
    const float* Bre    = (const float*)d_in[6];
    const float* Bim    = (const float*)d_in[7];
    const float* Cre    = (const float*)d_in[8];
    const float* Cim    = (const float*)d_in[9];
    const float* Dp     = (const float*)d_in[10];
    const float* s4oW   = (const float*)d_in[11];
    const float* s4ob   = (const float*)d_in[12];
    const float* lin1W  = (const float*)d_in[13];
    const float* lin1b  = (const float*)d_in[14];
    const float* lin2W  = (const float*)d_in[15];
    const float* lin2b  = (const float*)d_in[16];
    const float* headW[2] = {(const float*)d_in[17], (const float*)d_in[21]};
    const float* headb[2] = {(const float*)d_in[18], (const float*)d_in[22]};
    const float* projW[2] = {(const float*)d_in[19], (const float*)d_in[23]};
    const float* projb[2] = {(const float*)d_in[20], (const float*)d_in[24]};

    char* w = (char*)d_ws;
    ushort_t* A0 = (ushort_t*)w;  w += (size_t)TOK * DM * 2;
    ushort_t* A1 = (ushort_t*)w;  w += (size_t)TOK * DM * 2;
    ushort_t* A2 = (ushort_t*)w;  w += (size_t)TOK * DM * 2;
    float2* dtA  = (float2*)w;    w += (size_t)NL * DM * NST * 8;
    float2* lam  = (float2*)w;    w += (size_t)NL * DM * NST * 8;
    float2* lamT = (float2*)w;    w += (size_t)NL * DM * NST * 8;
    float2* CB   = (float2*)w;    w += (size_t)NL * DM * NST * 8;
    float2* P    = (float2*)w;    w += (size_t)BSZ * DM * NCH * NST * 8;  // 16 MiB
    float2* Wtab = (float2*)w;    w += (size_t)DM * NST * TC * 8;
    float*  KtabC = (float*)w;    w += (size_t)DM * TC * 4;
    ushort_t* wb = (ushort_t*)w;  w += (size_t)655360 * 2;
    float*  bc   = (float*)w;     w += 512 * 4;
    if ((size_t)(w - (char*)d_ws) > ws_size) return;   // ~46 MiB (proven)
    ushort_t* F = (ushort_t*)P;

    ushort_t* WB_lin2[2] = {wb + 0,      wb + 65536};
    ushort_t* WB_head0   = wb + 131072;
    ushort_t* WB_proj0   = wb + 196608;
    ushort_t* WB_head1   = wb + 262144;
    ushort_t* WB_proj1   = wb + 393216;
    ushort_t* WBc[2]     = {wb + 524288, wb + 589824};

    k_setup_modes<<<NL * DM * NST / 256, 256, 0, stream>>>(
        log_dt, Alr, Aim, Bre, Bim, Cre, Cim, dtA, lam, lamT, CB);
    for (int i = 0; i < NL; ++i) {
        size_t wf = (size_t)i * DM * DM;
        k_wcvt<<<256, 256, 0, stream>>>(lin2W + wf, WB_lin2[i], DM);
        k_wc_fuse<<<256, 256, 0, stream>>>(s4oW + wf, lin1W + wf, WBc[i]);
        k_bc_fuse<<<1, 256, 0, stream>>>(s4ob + i * DM, lin1W + wf, lin1b + i * DM,
                                         bc + i * 256);
    }
    k_wcvt<<<256, 256, 0, stream>>>(headW[0], WB_head0, DM);
    k_wcvt<<<256, 256, 0, stream>>>(projW[0], WB_proj0, DM);
    k_wcvt<<<512, 256, 0, stream>>>(headW[1], WB_head1, 2 * DM);
    k_wcvt<<<512, 256, 0, stream>>>(projW[1], WB_proj1, 2 * DM);
    {
        dim3 gt(LSEQ / 32, DM / 32, BSZ);
        dim3 bt(32, 8);
        k_transpose_in<<<gt, bt, 0, stream>>>(x, A0);
    }

    dim3 gg(TOK / 64, DM / 64);
    for (int i = 0; i < NL; ++i) {
        ushort_t* U = (i == 0) ? A0 : A2;
        ushort_t* T = (i == 0) ? A1 : A0;
        ushort_t* G = (i == 0) ? A2 : A1;
        size_t off = (size_t)i * DM * NST;

        k_layernorm_T<<<TOK, DM, 0, stream>>>(U, T, ln_g + (2 * i) * DM,
                                              ln_b + (2 * i) * DM);
        k_setup_wk<<<DM * TC / 128, 128, 0, stream>>>(dtA + off, lam + off,
                                                      CB + off, KtabC, Wtab);
        {
            dim3 gs(NCH, DM / 8, BSZ);
            k_chunk_states<<<gs, 256, 0, stream>>>(T, lam + off, P);
        }
        k_chunk_scan<<<BSZ * DM * NST / 256, 256, 0, stream>>>(lamT + off, P);
        {
            dim3 gc(NCH / 4, DM);
            k_conv_out<<<gc, 128, 0, stream>>>(T, G, KtabC, Wtab, P, Dp + i * DM);
        }
        // o1 = G@Wc + bc + U -> T
        k_gemm_mfma<<<gg, 256, 0, stream>>>(G, WBc[i], bc + i * 256, U, T, DM, 0);
        // LN2(T) -> G
        k_layernorm<<<TOK, DM, 0, stream>>>(T, G, ln_g + (2 * i + 1) * DM,
                                            ln_b + (2 * i + 1) * DM);
        // g2 = gelu(G@lin2) -> U
        k_gemm_mfma<<<gg, 256, 0, stream>>>(G, WB_lin2[i], lin2b + i * DM, 0, U, DM, 1);
        if (i == 0) {
            k_gemm2_mfma<<<gg, 256, 0, stream>>>(U, WB_head0, T, WB_proj0,
                                                 headb[0], projb[0], A2, DM, 0);
        } else {
            dim3 gh(TOK / 64, 2 * DM / 64);
            k_gemm2_mfma<<<gh, 256, 0, stream>>>(U, WB_head1, T, WB_proj1,
                                                 headb[1], projb[1], F, 2 * DM, 8);
        }
    }
    {
        dim3 gf(LSEQ / 32, 2 * DM / 32, BSZ);
        dim3 bf(32, 8);
        k_final_out<<<gf, bf, 0, stream>>>(F, out);
    }
}

// Round 21
// 458.034 us; speedup vs baseline: 2.8769x; 1.1018x over previous
//
#include <hip/hip_runtime.h>

// S4MaskNet: 2-layer S4, B=8, D=256, L=2048, N=32. Inputs f32, OUTPUT f32.
// r21: conv_out -> MFMA formulation. Per h: [Ktri | 2*W~](64x128) @
// [U; S](128x256) + dp*u + gelu. Kills Toeplitz wave-divergence (G5) and
// puts the conv on the matrix cores (G10). Rest identical to r20.

#define BSZ 8
#define DM 256
#define LSEQ 2048
#define NST 32
#define TC 64
#define NCH 32
#define TOK (BSZ*LSEQ)
#define NL 2

typedef __attribute__((ext_vector_type(8))) short bf16x8;
typedef __attribute__((ext_vector_type(4))) float f32x4;
typedef unsigned short ushort_t;

__device__ __forceinline__ float b2f(unsigned short v) {
    unsigned int u = ((unsigned int)v) << 16;
    float f;
    __builtin_memcpy(&f, &u, 4);
    return f;
}
__device__ __forceinline__ unsigned short f2b(float f) {
    unsigned int u;
    __builtin_memcpy(&u, &f, 4);
    unsigned int r = (u + 0x7FFFu + ((u >> 16) & 1u)) >> 16;   // RNE
    return (unsigned short)r;
}
__device__ __forceinline__ float gelu_f(float z) {
    float x = z * 0.70710678118654752f;
    float ax = fabsf(x);
    float t = 1.0f / (1.0f + 0.3275911f * ax);
    float poly = t * (0.254829592f + t * (-0.284496736f + t * (1.421413741f +
                 t * (-1.453152027f + t * 1.061405429f))));
    float erfax = 1.0f - poly * expf(-ax * ax);
    float er = (x < 0.0f) ? -erfax : erfax;
    return 0.5f * z * (1.0f + er);
}

// ---- setup: dtA, lambda, lambda^TC, CB ----
__global__ void k_setup_modes(const float* log_dt, const float* Alr, const float* Aim,
                              const float* Bre, const float* Bim,
                              const float* Cre, const float* Cim,
                              float2* dtA, float2* lam, float2* lamT, float2* CB) {
    int idx = blockIdx.x * blockDim.x + threadIdx.x;
    if (idx >= NL * DM * NST) return;
    int h = (idx >> 5) & (DM - 1);
    int i = idx >> 13;
    float dt  = expf(log_dt[i * DM + h]);
    float Are = -expf(Alr[idx]);
    float Ai  = Aim[idx];
    float dr = dt * Are, di = dt * Ai;
    float er = expf(dr);
    float lr = er * cosf(di), li = er * sinf(di);
    float inv = 1.0f / (Are * Are + Ai * Ai);
    float e1r = lr - 1.0f, e1i = li;
    float tr = (e1r * Are + e1i * Ai) * inv;
    float ti = (e1i * Are - e1r * Ai) * inv;
    float br = Bre[idx], bi = Bim[idx];
    float dBr = br * tr - bi * ti, dBi = br * ti + bi * tr;
    float cr = Cre[idx], ci = Cim[idx];
    dtA[idx] = make_float2(dr, di);
    lam[idx] = make_float2(lr, li);
    CB[idx]  = make_float2(cr * dBr - ci * dBi, cr * dBi + ci * dBr);
    float pr = lr, pi = li;
    for (int s = 0; s < 6; ++s) { float nr = pr * pr - pi * pi; pi = 2.f * pr * pi; pr = nr; }
    lamT[idx] = make_float2(pr, pi);
}

// ---- weight convert+transpose: W[k][N] f32 -> WBt[n][256] bf16 ----
__global__ void k_wcvt(const float* src, ushort_t* dst, int N) {
    int idx = blockIdx.x * 256 + threadIdx.x;
    if (idx >= N * 256) return;
    int n = idx >> 8, k = idx & 255;
    dst[idx] = f2b(src[(size_t)k * N + n]);
}

// ---- fused weight: WBc[c][r] = bf16( sum_k s4oW[r,k]*lin1W[k,c] ) ----
__global__ void k_wc_fuse(const float* Wa, const float* Wb, ushort_t* WBc) {
    int c = blockIdx.x;
    int r = threadIdx.x;
    const float* ar = Wa + (size_t)r * 256;
    float s = 0.f;
    for (int k = 0; k < 256; ++k) s = fmaf(ar[k], Wb[(size_t)k * 256 + c], s);
    WBc[(size_t)c * 256 + r] = f2b(s);
}
__global__ void k_bc_fuse(const float* s4ob, const float* Wb, const float* lin1b,
                          float* bc) {
    int c = threadIdx.x;
    float s = lin1b[c];
    for (int k = 0; k < 256; ++k) s = fmaf(s4ob[k], Wb[(size_t)k * 256 + c], s);
    bc[c] = s;
}

// ---- chunk tables ----
__global__ void k_setup_wk(const float2* dtA_l, const float2* lam_l, const float2* CB_l,
                           float* Ktab, float2* Wtab) {
    int idx = blockIdx.x * blockDim.x + threadIdx.x;
    if (idx >= DM * TC) return;
    int t = idx & (TC - 1);
    int h = idx >> 6;
    int base = h * NST;
    float ft = (float)t;
    float Ks = 0.f;
    for (int n = 0; n < NST; ++n) {
        float2 d = dtA_l[base + n]; float2 l1 = lam_l[base + n]; float2 cb = CB_l[base + n];
        float er = expf(d.x * ft);
        float cs = cosf(d.y * ft), sn = sinf(d.y * ft);
        float ltr = er * cs, lti = er * sn;
        Ks += cb.x * ltr - cb.y * lti;
        float p1r = ltr * l1.x - lti * l1.y, p1i = ltr * l1.y + lti * l1.x;
        Wtab[(h * NST + n) * TC + t] =
            make_float2(cb.x * p1r - cb.y * p1i, cb.x * p1i + cb.y * p1r);
    }
    Ktab[idx] = 2.f * Ks;
}

// ---- x [B, D, L] f32 -> o [B, L, D] bf16 ----
__global__ void k_transpose_in(const float* x, ushort_t* o) {
    __shared__ float tile[32][33];
    int b = blockIdx.z;
    int l0 = blockIdx.x * 32, d0 = blockIdx.y * 32;
    int tx = threadIdx.x, ty = threadIdx.y;
    for (int k = 0; k < 4; ++k)
        tile[ty + 8 * k][tx] = x[((size_t)b * DM + d0 + ty + 8 * k) * LSEQ + l0 + tx];
    __syncthreads();
    for (int k = 0; k < 4; ++k)
        o[((size_t)b * LSEQ + l0 + ty + 8 * k) * DM + d0 + tx] = f2b(tile[tx][ty + 8 * k]);
}

// ---- layernorm -> token-major ----
__global__ void k_layernorm(const ushort_t* src, ushort_t* dst,
                            const float* g, const float* bb) {
    __shared__ float r1[DM];
    __shared__ float r2[DM];
    int tok = blockIdx.x;
    int d = threadIdx.x;
    float v = b2f(src[(size_t)tok * DM + d]);
    r1[d] = v;
    r2[d] = v * v;
    __syncthreads();
    for (int s = DM / 2; s > 0; s >>= 1) {
        if (d < s) { r1[d] += r1[d + s]; r2[d] += r2[d + s]; }
        __syncthreads();
    }
    float m = r1[0] * (1.0f / DM);
    float var = r2[0] * (1.0f / DM) - m * m;
    float inv = rsqrtf(var + 1e-5f);
    dst[(size_t)tok * DM + d] = f2b((v - m) * inv * g[d] + bb[d]);
}

// ---- layernorm -> h-major transposed ----
__global__ void k_layernorm_T(const ushort_t* src, ushort_t* dstT,
                              const float* g, const float* bb) {
    __shared__ float r1[DM];
    __shared__ float r2[DM];
    int tok = blockIdx.x;
    int d = threadIdx.x;
    float v = b2f(src[(size_t)tok * DM + d]);
    r1[d] = v;
    r2[d] = v * v;
    __syncthreads();
    for (int s = DM / 2; s > 0; s >>= 1) {
        if (d < s) { r1[d] += r1[d + s]; r2[d] += r2[d + s]; }
        __syncthreads();
    }
    float m = r1[0] * (1.0f / DM);
    float var = r2[0] * (1.0f / DM) - m * m;
    float inv = rsqrtf(var + 1e-5f);
    int b = tok >> 11, l = tok & 2047;
    dstT[((size_t)b * DM + d) * LSEQ + l] = f2b((v - m) * inv * g[d] + bb[d]);
}

// ---- chunk states from uT ----
__global__ void k_chunk_states(const ushort_t* uT, const float2* lam_l, float2* P) {
    int n = threadIdx.x & 31, hs = threadIdx.x >> 5;
    int c = blockIdx.x, h = blockIdx.y * 8 + hs, b = blockIdx.z;
    float2 lm = lam_l[h * NST + n];
    float sr = 0.f, si = 0.f;
    const ushort_t* up = uT + ((size_t)b * DM + h) * LSEQ + c * TC;
#pragma unroll 8
    for (int t = 0; t < TC; ++t) {
        float u = b2f(up[t]);
        float nr = fmaf(lm.x, sr, fmaf(-lm.y, si, u));
        float ni = fmaf(lm.x, si, lm.y * sr);
        sr = nr; si = ni;
    }
    P[(((size_t)b * DM + h) * NCH + c) * NST + n] = make_float2(sr, si);
}

// ---- scan ----
__global__ void k_chunk_scan(const float2* lamT_l, float2* P) {
    int idx = blockIdx.x * blockDim.x + threadIdx.x;
    if (idx >= BSZ * DM * NST) return;
    int n = idx & 31, h = (idx >> 5) & 255, b = idx >> 13;
    float2 lT = lamT_l[h * NST + n];
    float hr = 0.f, hi = 0.f;
    float2* base = P + (((size_t)b * DM + h) * NCH) * NST + n;
    for (int c = 0; c < NCH; ++c) {
        float2 p = base[(size_t)c * NST];
        base[(size_t)c * NST] = make_float2(hr, hi);
        float nr = fmaf(lT.x, hr, fmaf(-lT.y, hi, p.x));
        float ni = fmaf(lT.x, hi, fmaf(lT.y, hr, p.y));
        hr = nr; hi = ni;
    }
}

// ---- conv via MFMA: per h, [Ktri | 2W~](64x128) @ [U; S](128x256) ----
// Y[t,bc] = sum_{s<=t} K[t-s] u[s,bc] + 2Re sum_n W[n][t] S[n,bc];
// z = Y + dp*u; G[token-major] = gelu(z).
__global__ void k_conv_mfma(const ushort_t* uT, ushort_t* G, const float* Ktab,
                            const float2* Wtab, const float2* P, const float* Dp_l) {
    __shared__ ushort_t As[64][128];    // 16 KB
    __shared__ ushort_t Bs[256][128];   // 64 KB
    int h = blockIdx.x;
    int tid = threadIdx.x;
    int wv = tid >> 6, l = tid & 63;
    // stage A: cols 0..63 = Ktri (K[t-s], lower-tri); cols 64..127 = carry matrix
    for (int idx = tid; idx < 64 * 128; idx += 256) {
        int r = idx >> 7, e = idx & 127;
        float v;
        if (e < 64) {
            int d = r - e;
            v = (d >= 0) ? Ktab[h * TC + d] : 0.f;
        } else {
            int j = e - 64;
            float2 wc = Wtab[((size_t)h * NST + (j >> 1)) * TC + r];
            v = (j & 1) ? -2.f * wc.y : 2.f * wc.x;
        }
        As[r][e ^ ((r & 7) << 3)] = f2b(v);
    }
    // stage B rows bc = b*32+c: k 0..63 = u (contig from uT), k 64..127 = S (re,im)
    for (int idx = tid; idx < 256 * 8; idx += 256) {
        int row = idx >> 3, ch = (idx & 7) * 8;
        int b = row >> 5, c = row & 31;
        bf16x8 v = *(const bf16x8*)(uT + ((size_t)b * DM + h) * LSEQ + c * TC + ch);
        *(bf16x8*)(&Bs[row][ch ^ ((row & 7) << 3)]) = v;
    }
    for (int idx = tid; idx < 256 * 32; idx += 256) {
        int row = idx >> 5, n = idx & 31;
        int b = row >> 5, c = row & 31;
        float2 s = P[(((size_t)b * DM + h) * NCH + c) * NST + n];
        int x = (row & 7) << 3;
        Bs[row][(64 + 2 * n) ^ x]     = f2b(s.x);
        Bs[row][(64 + 2 * n + 1) ^ x] = f2b(s.y);
    }
    __syncthreads();
    int lr = l & 15, lk = (l >> 4) * 8;
    int ax = (lr & 7) << 3;
    f32x4 acc[16];
#pragma unroll
    for (int i = 0; i < 16; ++i) acc[i] = (f32x4){0.f, 0.f, 0.f, 0.f};
#pragma unroll
    for (int k0 = 0; k0 < 128; k0 += 32) {
        bf16x8 a = *(const bf16x8*)(&As[wv * 16 + lr][(lk + k0) ^ ax]);
#pragma unroll
        for (int nt = 0; nt < 16; ++nt) {
            bf16x8 b = *(const bf16x8*)(&Bs[nt * 16 + lr][(lk + k0) ^ ax]);
            acc[nt] = __builtin_amdgcn_mfma_f32_16x16x32_bf16(a, b, acc[nt], 0, 0, 0);
        }
    }
    float dp = Dp_l[h];
#pragma unroll
    for (int nt = 0; nt < 16; ++nt) {
        int bc = nt * 16 + (l & 15);
        int b = bc >> 5, c = bc & 31;
        int bx = (bc & 7) << 3;
#pragma unroll
        for (int r = 0; r < 4; ++r) {
            int t = wv * 16 + (l >> 4) * 4 + r;   // C/D row = (l>>4)*4+r per tile
            float uv = b2f(Bs[bc][t ^ bx]);
            float z = acc[nt][r] + dp * uv;
            G[((size_t)b * LSEQ + c * TC + t) * DM + h] = f2b(gelu_f(z));
        }
    }
}

// ==== LDS-staged MFMA GEMM machinery (r20, validated) ====
__device__ __forceinline__ void stage_tile(const ushort_t* src, int row0,
                                           ushort_t (*dst)[256], int tid) {
    for (int idx = tid; idx < 64 * 32; idx += 256) {
        int r = idx >> 5, ch = (idx & 31) * 8;
        bf16x8 v = *(const bf16x8*)(src + (size_t)(row0 + r) * 256 + ch);
        *(bf16x8*)(&dst[r][ch ^ ((r & 7) << 3)]) = v;
    }
}
__device__ __forceinline__ void mma_tile(const ushort_t (*As)[256],
                                         const ushort_t (*Bs)[256],
                                         int wv, int l, f32x4* acc) {
    int lr = l & 15, lk = (l >> 4) * 8;
    int ax = (lr & 7) << 3;
#pragma unroll
    for (int k0 = 0; k0 < 256; k0 += 32) {
        bf16x8 a  = *(const bf16x8*)(&As[wv * 16 + lr][(lk + k0) ^ ax]);
        bf16x8 b0 = *(const bf16x8*)(&Bs[lr]          [(lk + k0) ^ ax]);
        bf16x8 b1 = *(const bf16x8*)(&Bs[16 + lr]     [(lk + k0) ^ ax]);
        bf16x8 b2 = *(const bf16x8*)(&Bs[32 + lr]     [(lk + k0) ^ ax]);
        bf16x8 b3 = *(const bf16x8*)(&Bs[48 + lr]     [(lk + k0) ^ ax]);
        acc[0] = __builtin_amdgcn_mfma_f32_16x16x32_bf16(a, b0, acc[0], 0, 0, 0);
        acc[1] = __builtin_amdgcn_mfma_f32_16x16x32_bf16(a, b1, acc[1], 0, 0, 0);
        acc[2] = __builtin_amdgcn_mfma_f32_16x16x32_bf16(a, b2, acc[2], 0, 0, 0);
        acc[3] = __builtin_amdgcn_mfma_f32_16x16x32_bf16(a, b3, acc[3], 0, 0, 0);
    }
}

__global__ void k_gemm_mfma(const ushort_t* A, const ushort_t* WBt,
                            const float* bias, const ushort_t* res,
                            ushort_t* C, int N, int flags) {
    __shared__ ushort_t As[64][256];
    __shared__ ushort_t Bs[64][256];
    int m0 = blockIdx.x * 64, n0 = blockIdx.y * 64;
    int tid = threadIdx.x;
    int wv = tid >> 6, l = tid & 63;
    stage_tile(A, m0, As, tid);
    stage_tile(WBt, n0, Bs, tid);
    __syncthreads();
    f32x4 acc[4] = {{0,0,0,0},{0,0,0,0},{0,0,0,0},{0,0,0,0}};
    mma_tile(As, Bs, wv, l, acc);
    int em = m0 + wv * 16 + (l >> 4) * 4;
    int en = n0 + (l & 15);
#pragma unroll
    for (int nt = 0; nt < 4; ++nt) {
        int n = en + nt * 16;
        float bsv = bias[n];
#pragma unroll
        for (int r = 0; r < 4; ++r) {
            int m = em + r;
            float v = acc[nt][r] + bsv;
            if (res) v += b2f(res[(size_t)m * DM + n]);
            if (flags & 1) v = gelu_f(v);
            if (flags & 8) v = fmaxf(v, 0.0f);
            C[(size_t)m * N + n] = f2b(v);
        }
    }
}

__global__ void k_gemm2_mfma(const ushort_t* Aa, const ushort_t* WBa,
                             const ushort_t* Ab, const ushort_t* WBb,
                             const float* biasA, const float* biasB,
                             ushort_t* C, int N, int flags) {
    __shared__ ushort_t As[64][256];
    __shared__ ushort_t Bs[64][256];
    int m0 = blockIdx.x * 64, n0 = blockIdx.y * 64;
    int tid = threadIdx.x;
    int wv = tid >> 6, l = tid & 63;
    f32x4 acc[4] = {{0,0,0,0},{0,0,0,0},{0,0,0,0},{0,0,0,0}};
    stage_tile(Aa, m0, As, tid);
    stage_tile(WBa, n0, Bs, tid);
    __syncthreads();
    mma_tile(As, Bs, wv, l, acc);
    __syncthreads();
    stage_tile(Ab, m0, As, tid);
    stage_tile(WBb, n0, Bs, tid);
    __syncthreads();
    mma_tile(As, Bs, wv, l, acc);
    int em = m0 + wv * 16 + (l >> 4) * 4;
    int en = n0 + (l & 15);
#pragma unroll
    for (int nt = 0; nt < 4; ++nt) {
        int n = en + nt * 16;
        float bsv = biasA[n] + biasB[n];
#pragma unroll
        for (int r = 0; r < 4; ++r) {
            int m = em + r;
            float v = acc[nt][r] + bsv;
            if (flags & 8) v = fmaxf(v, 0.0f);
            C[(size_t)m * N + n] = f2b(v);
        }
    }
}

// ---- final: F [B,L,512] bf16 -> out [2,B,256,L] f32 ----
__global__ void k_final_out(const ushort_t* F, float* out) {
    __shared__ float tile[32][33];
    int b = blockIdx.z;
    int l0 = blockIdx.x * 32, c0 = blockIdx.y * 32;
    int tx = threadIdx.x, ty = threadIdx.y;
    for (int k = 0; k < 4; ++k)
        tile[ty + 8 * k][tx] = b2f(F[((size_t)(b * LSEQ + l0 + ty + 8 * k)) * 512 + c0 + tx]);
    __syncthreads();
    for (int k = 0; k < 4; ++k) {
        int cg = c0 + ty + 8 * k;
        int s = cg >> 8, cc = cg & 255;
        out[(((size_t)s * BSZ + b) * DM + cc) * LSEQ + l0 + tx] = tile[tx][ty + 8 * k];
    }
}

// ---- launcher ----
extern "C" void kernel_launch(void* const* d_in, const int* in_sizes, int n_in,
                              void* d_out, int out_size, void* d_ws, size_t ws_size,
                              hipStream_t stream) {
    (void)in_sizes; (void)n_in; (void)out_size;
    float* out = (float*)d_out;

    const float* x      = (const float*)d_in[0];
    const float* ln_g   = (const float*)d_in[1];
    const float* ln_b   = (const float*)d_in[2];
    const float* log_dt = (const float*)d_in[3];
    const float* Alr    = (const float*)d_in[4];
    const float* Aim    = (const float*)d_in[5];
    const float* Bre    = (const float*)d_in[6];
    const float* Bim    = (const float*)d_in[7];
    const float* Cre    = (const float*)d_in[8];
    const float* Cim    = (const float*)d_in[9];
    const float* Dp     = (const float*)d_in[10];
    const float* s4oW   = (const float*)d_in[11];
    const float* s4ob   = (const float*)d_in[12];
    const float* lin1W  = (const float*)d_in[13];
    const float* lin1b  = (const float*)d_in[14];
    const float* lin2W  = (const float*)d_in[15];
    const float* lin2b  = (const float*)d_in[16];
    const float* headW[2] = {(const float*)d_in[17], (const float*)d_in[21]};
    const float* headb[2] = {(const float*)d_in[18], (const float*)d_in[22]};
    const float* projW[2] = {(const float*)d_in[19], (const float*)d_in[23]};
    const float* projb[2] = {(const float*)d_in[20], (const float*)d_in[24]};

    char* w = (char*)d_ws;
    ushort_t* A0 = (ushort_t*)w;  w += (size_t)TOK * DM * 2;
    ushort_t* A1 = (ushort_t*)w;  w += (size_t)TOK * DM * 2;
    ushort_t* A2 = (ushort_t*)w;  w += (size_t)TOK * DM * 2;
    float2* dtA  = (float2*)w;    w += (size_t)NL * DM * NST * 8;
    float2* lam  = (float2*)w;    w += (size_t)NL * DM * NST * 8;
    float2* lamT = (float2*)w;    w += (size_t)NL * DM * NST * 8;
    float2* CB   = (float2*)w;    w += (size_t)NL * DM * NST * 8;
    float2* P    = (float2*)w;    w += (size_t)BSZ * DM * NCH * NST * 8;  // 16 MiB
    float2* Wtab = (float2*)w;    w += (size_t)DM * NST * TC * 8;
    float*  KtabC = (float*)w;    w += (size_t)DM * TC * 4;
    ushort_t* wb = (ushort_t*)w;  w += (size_t)655360 * 2;
    float*  bc   = (float*)w;     w += 512 * 4;
    if ((size_t)(w - (char*)d_ws) > ws_size) return;   // ~46 MiB (proven)
    ushort_t* F = (ushort_t*)P;

    ushort_t* WB_lin2[2] = {wb + 0,      wb + 65536};
    ushort_t* WB_head0   = wb + 131072;
    ushort_t* WB_proj0   = wb + 196608;
    ushort_t* WB_head1   = wb + 262144;
    ushort_t* WB_proj1   = wb + 393216;
    ushort_t* WBc[2]     = {wb + 524288, wb + 589824};

    k_setup_modes<<<NL * DM * NST / 256, 256, 0, stream>>>(
        log_dt, Alr, Aim, Bre, Bim, Cre, Cim, dtA, lam, lamT, CB);
    for (int i = 0; i < NL; ++i) {
        size_t wf = (size_t)i * DM * DM;
        k_wcvt<<<256, 256, 0, stream>>>(lin2W + wf, WB_lin2[i], DM);
        k_wc_fuse<<<256, 256, 0, stream>>>(s4oW + wf, lin1W + wf, WBc[i]);
        k_bc_fuse<<<1, 256, 0, stream>>>(s4ob + i * DM, lin1W + wf, lin1b + i * DM,
                                         bc + i * 256);
    }
    k_wcvt<<<256, 256, 0, stream>>>(headW[0], WB_head0, DM);
    k_wcvt<<<256, 256, 0, stream>>>(projW[0], WB_proj0, DM);
    k_wcvt<<<512, 256, 0, stream>>>(headW[1], WB_head1, 2 * DM);
    k_wcvt<<<512, 256, 0, stream>>>(projW[1], WB_proj1, 2 * DM);
    {
        dim3 gt(LSEQ / 32, DM / 32, BSZ);
        dim3 bt(32, 8);
        k_transpose_in<<<gt, bt, 0, stream>>>(x, A0);
    }

    dim3 gg(TOK / 64, DM / 64);
    for (int i = 0; i < NL; ++i) {
        ushort_t* U = (i == 0) ? A0 : A2;
        ushort_t* T = (i == 0) ? A1 : A0;
        ushort_t* G = (i == 0) ? A2 : A1;
        size_t off = (size_t)i * DM * NST;

        k_layernorm_T<<<TOK, DM, 0, stream>>>(U, T, ln_g + (2 * i) * DM,
                                              ln_b + (2 * i) * DM);
        k_setup_wk<<<DM * TC / 128, 128, 0, stream>>>(dtA + off, lam + off,
                                                      CB + off, KtabC, Wtab);
        {
            dim3 gs(NCH, DM / 8, BSZ);
            k_chunk_states<<<gs, 256, 0, stream>>>(T, lam + off, P);
        }
        k_chunk_scan<<<BSZ * DM * NST / 256, 256, 0, stream>>>(lamT + off, P);
        k_conv_mfma<<<DM, 256, 0, stream>>>(T, G, KtabC, Wtab, P, Dp + i * DM);
        // o1 = G@Wc + bc + U -> T
        k_gemm_mfma<<<gg, 256, 0, stream>>>(G, WBc[i], bc + i * 256, U, T, DM, 0);
        // LN2(T) -> G
        k_layernorm<<<TOK, DM, 0, stream>>>(T, G, ln_g + (2 * i + 1) * DM,
                                            ln_b + (2 * i + 1) * DM);
        // g2 = gelu(G@lin2) -> U
        k_gemm_mfma<<<gg, 256, 0, stream>>>(G, WB_lin2[i], lin2b + i * DM, 0, U, DM, 1);
        if (i == 0) {
            k_gemm2_mfma<<<gg, 256, 0, stream>>>(U, WB_head0, T, WB_proj0,
                                                 headb[0], projb[0], A2, DM, 0);
        } else {
            dim3 gh(TOK / 64, 2 * DM / 64);
            k_gemm2_mfma<<<gh, 256, 0, stream>>>(U, WB_head1, T, WB_proj1,
                                                 headb[1], projb[1], F, 2 * DM, 8);
        }
    }
    {
        dim3 gf(LSEQ / 32, 2 * DM / 32, BSZ);
        dim3 bf(32, 8);
        k_final_out<<<gf, bf, 0, stream>>>(F, out);
    }
}